// Round 5
// baseline (848.785 us; speedup 1.0000x reference)
//
#include <hip/hip_runtime.h>
#include <hip/hip_bf16.h>
#include <cstddef>

typedef unsigned short u16;
typedef __attribute__((ext_vector_type(8))) short bf16x8;
typedef __attribute__((ext_vector_type(4))) float f32x4;

#define C2 0.18033688011112042f   // 0.125 * log2(e)

__device__ __forceinline__ u16 f2b(float f) {
    unsigned u = __builtin_bit_cast(unsigned, f);
    unsigned r = (u + 0x7FFF + ((u >> 16) & 1)) >> 16;
    return (u16)r;
}

__device__ __forceinline__ float exp2a(float x) {
    float r; asm("v_exp_f32 %0, %1" : "=v"(r) : "v"(x)); return r;
}

__device__ __forceinline__ unsigned cvtpk(float lo, float hi) {
    unsigned r; asm("v_cvt_pk_bf16_f32 %0, %1, %2" : "=v"(r) : "v"(lo), "v"(hi));
    return r;
}

__device__ __forceinline__ void gload_lds16(const void* g, void* l) {
    __builtin_amdgcn_global_load_lds(
        (const __attribute__((address_space(1))) unsigned int*)g,
        (__attribute__((address_space(3))) unsigned int*)l, 16, 0, 0);
}

#define VDRAIN() asm volatile("s_waitcnt vmcnt(0)" ::: "memory")
#define SBAR() do { __builtin_amdgcn_sched_barrier(0); __builtin_amdgcn_s_barrier(); } while (0)

// ---------------- elementwise fp32 -> bf16 ----------------
__global__ __launch_bounds__(256) void cvt_bf16(const float* __restrict__ in,
                                                u16* __restrict__ out, int n4)
{
    int i = blockIdx.x * 256 + threadIdx.x;
    if (i >= n4) return;
    float4 v = ((const float4*)in)[i];
    union { u16 s[4]; uint2 u; } pk;
    pk.s[0] = f2b(v.x); pk.s[1] = f2b(v.y); pk.s[2] = f2b(v.z); pk.s[3] = f2b(v.w);
    ((uint2*)out)[i] = pk.u;
}

// ---------------- kv_input concat (bf16) ----------------
__global__ __launch_bounds__(256) void concat_bf16(
    const float* __restrict__ x, const float* __restrict__ mem,
    const float* __restrict__ cmem, u16* __restrict__ out)
{
    int rowg = blockIdx.x;               // 0..9215
    int b = rowg / 2304, rr = rowg % 2304;
    const float* src = (rr < 256)  ? cmem + ((size_t)b * 256 + rr) * 1024
                     : (rr < 1280) ? mem  + ((size_t)b * 1024 + (rr - 256)) * 1024
                                   : x    + ((size_t)b * 1024 + (rr - 1280)) * 1024;
    float4 v = ((const float4*)src)[threadIdx.x];
    union { u16 s[4]; uint2 u; } pk;
    pk.s[0] = f2b(v.x); pk.s[1] = f2b(v.y); pk.s[2] = f2b(v.z); pk.s[3] = f2b(v.w);
    ((uint2*)(out + (size_t)rowg * 1024))[threadIdx.x] = pk.u;
}

// ---------------- transpose fp32 [K][N] -> bf16 [N][K] ----------------
__global__ __launch_bounds__(256) void transpose_bf16(
    const float* __restrict__ in, u16* __restrict__ out, int K, int N)
{
    __shared__ float t[32][33];
    int k0 = blockIdx.y * 32, n0 = blockIdx.x * 32;
    int tx = threadIdx.x & 31, ty = threadIdx.x >> 5;
    #pragma unroll
    for (int p = 0; p < 4; ++p)
        t[ty + 8 * p][tx] = in[(size_t)(k0 + ty + 8 * p) * N + n0 + tx];
    __syncthreads();
    #pragma unroll
    for (int p = 0; p < 4; ++p)
        out[(size_t)(n0 + ty + 8 * p) * K + k0 + tx] = f2b(t[tx][ty + 8 * p]);
}

// ---------------- conv_w[o,i,r] -> W2t[o][r*1024+i] bf16 ----------------
__global__ __launch_bounds__(256) void w2t_bf16(const float* __restrict__ cw,
                                                u16* __restrict__ out)
{
    size_t idx = (size_t)blockIdx.x * 256 + threadIdx.x;  // 1024*4096
    int o = (int)(idx >> 12), k = (int)(idx & 4095);
    out[idx] = f2b(cw[(size_t)o * 4096 + (k & 1023) * 4 + (k >> 10)]);
}

// ---------------- V half of [rows][2048] -> Vt[(bh*64+d)][rows] ----------------
__global__ __launch_bounds__(256) void transpose_v(
    const u16* __restrict__ src, int R, u16* __restrict__ dst)
{
    __shared__ u16 t[64 * 65];
    int bh = blockIdx.y, b = bh >> 4, h = bh & 15;
    int j0 = blockIdx.x * 64;
    int tid = threadIdx.x;
    #pragma unroll
    for (int p = 0; p < 2; ++p) {
        int idx = tid + p * 256;
        int j = idx >> 3, c = idx & 7;
        uint4 v = *(const uint4*)(src + ((size_t)(b * R + j0 + j)) * 2048 + 1024 + h * 64 + c * 8);
        const u16* vv = (const u16*)&v;
        #pragma unroll
        for (int u2 = 0; u2 < 8; ++u2) t[j * 65 + c * 8 + u2] = vv[u2];
    }
    __syncthreads();
    #pragma unroll
    for (int p = 0; p < 2; ++p) {
        int idx = tid + p * 256;
        int jc = idx & 7, d = idx >> 3;
        union { u16 s[8]; uint4 u; } pk;
        #pragma unroll
        for (int u2 = 0; u2 < 8; ++u2) pk.s[u2] = t[(jc * 8 + u2) * 65 + d];
        *(uint4*)(dst + ((size_t)(bh * 64 + d)) * (size_t)R + j0 + jc * 8) = pk.u;
    }
}

// ---------------- bf16 MFMA GEMM: C[M,N] = A[M,K] @ Bt[N,K]^T (+bias) ----------------
__global__ __launch_bounds__(256) void gemm_bf16(
    const u16* __restrict__ A, const u16* __restrict__ Bt,
    const float* __restrict__ bias, float* __restrict__ Cf,
    u16* __restrict__ Cb, int M, int N, int K)
{
    __shared__ u16 Al[128 * 32];
    __shared__ u16 Bl[128 * 32];
    const int tid = threadIdx.x, w = tid >> 6, lane = tid & 63;
    const int lr = lane & 15, lg = lane >> 4;
    const int bm0 = blockIdx.y * 128, bn0 = blockIdx.x * 128;
    const int wr = (w >> 1) * 64, wc = (w & 1) * 64;

    f32x4 acc[4][4];
    const f32x4 z = {0.f, 0.f, 0.f, 0.f};
    #pragma unroll
    for (int mb = 0; mb < 4; ++mb)
        #pragma unroll
        for (int nb = 0; nb < 4; ++nb) acc[mb][nb] = z;

    for (int k0 = 0; k0 < K; k0 += 32) {
        __syncthreads();
        #pragma unroll
        for (int q = 0; q < 2; ++q) {
            int chunk = w * 2 + q;
            int row = chunk * 16 + (lane >> 2);
            int sg = (lane & 3) * 8;
            gload_lds16(A + (size_t)(bm0 + row) * K + k0 + sg, &Al[chunk * 512]);
            gload_lds16(Bt + (size_t)(bn0 + row) * K + k0 + sg, &Bl[chunk * 512]);
        }
        __syncthreads();
        bf16x8 af[4], bf[4];
        #pragma unroll
        for (int mb = 0; mb < 4; ++mb)
            af[mb] = *(const bf16x8*)&Al[(wr + mb * 16 + lr) * 32 + lg * 8];
        #pragma unroll
        for (int nb = 0; nb < 4; ++nb)
            bf[nb] = *(const bf16x8*)&Bl[(wc + nb * 16 + lr) * 32 + lg * 8];
        #pragma unroll
        for (int mb = 0; mb < 4; ++mb)
            #pragma unroll
            for (int nb = 0; nb < 4; ++nb)
                acc[mb][nb] = __builtin_amdgcn_mfma_f32_16x16x32_bf16(
                    af[mb], bf[nb], acc[mb][nb], 0, 0, 0);
    }

    #pragma unroll
    for (int mb = 0; mb < 4; ++mb)
        #pragma unroll
        for (int nb = 0; nb < 4; ++nb)
            #pragma unroll
            for (int jr = 0; jr < 4; ++jr) {
                int row = bm0 + wr + mb * 16 + lg * 4 + jr;
                int col = bn0 + wc + nb * 16 + lr;
                float v = acc[mb][nb][jr] + (bias ? bias[col] : 0.f);
                if (Cf) Cf[(size_t)row * N + col] = v;
                if (Cb) Cb[(size_t)row * N + col] = f2b(v);
            }
}

// ---------------- fused main attention + aux phase-0 ----------------
// LDS exactly 40960 B -> 4 blocks/CU.
__global__ __launch_bounds__(256, 4) void attn_main_fused(
    const u16* __restrict__ qb,    // (4,1024,1024) bf16
    const u16* __restrict__ kvb,   // (4,2304,2048) bf16 k|v
    const u16* __restrict__ vt,    // (64bh*64d, 2304) bf16  V^T
    const u16* __restrict__ peb,   // (16,2304,64) bf16
    u16* __restrict__ outb,        // (4,1024,1024) bf16
    float* __restrict__ auxo)      // (64bh,1024,64) fp32 aux phase-0 out
{
    __shared__ u16 kbuf[64 * 64];      // 8 KB
    __shared__ u16 vbuf[64 * 64];      // 8 KB  [d][j-chunks] swizzled
    __shared__ u16 pering[128 * 64];   // 16 KB ring
    __shared__ u16 pls[4][1024];       // 8 KB, XOR-swizzled P

    const int tid = threadIdx.x;
    const int w = tid >> 6, lane = tid & 63;
    const int lr = lane & 15, lg = lane >> 4;
    const int rl = lane >> 3, cch = lane & 7;
    const int bh = blockIdx.y, b = bh >> 4, h = bh & 15;
    const int i0 = blockIdx.x * 64;
    const int iw = i0 + 16 * w;
    const int jb0 = 960 - i0;

    // per-thread constant pls indices
    const int lrh = lr >> 3, lrm = lr & 7;
    int pwidx[4], pridx[2];
    #pragma unroll
    for (int nb = 0; nb < 4; ++nb)
        pwidx[nb] = (((nb * 2 + lrh) ^ (lg * 2)) * 8) + lrm;
    #pragma unroll
    for (int ks = 0; ks < 2; ++ks)
        pridx[ks] = lr * 64 + (((ks * 4 + lg) ^ ((lr >> 2) * 2)) * 8);

    bf16x8 qf[2];
    #pragma unroll
    for (int ks = 0; ks < 2; ++ks)
        qf[ks] = *(const bf16x8*)(qb + ((size_t)(b * 1024 + iw + lr)) * 1024
                                  + h * 64 + ks * 32 + lg * 8);

    const f32x4 z = {0.f, 0.f, 0.f, 0.f};
    f32x4 od[4], od2[4];
    float mloc[4], lloc[4], ml2[4], ll2[4];
    #pragma unroll
    for (int nb = 0; nb < 4; ++nb) { od[nb] = z; od2[nb] = z; }
    #pragma unroll
    for (int jr = 0; jr < 4; ++jr) {
        mloc[jr] = -1e30f; lloc[jr] = 0.f;
        ml2[jr] = -1e30f; ll2[jr] = 0.f;
    }

    // ---- prologue: K(0), V(0), full 128-row PE band ----
    #pragma unroll
    for (int q = 0; q < 2; ++q) {
        int row = 16 * w + 8 * q + rl;
        gload_lds16(kvb + ((size_t)(b * 2304 + row)) * 2048 + h * 64 + ((cch ^ rl) * 8),
                    &kbuf[(16 * w + 8 * q) * 64]);
        gload_lds16(vt + ((size_t)(bh * 64 + row)) * 2304 + ((cch ^ rl) * 8),
                    &vbuf[(16 * w + 8 * q) * 64]);
    }
    #pragma unroll
    for (int q = 0; q < 4; ++q) {
        int rr = 32 * w + 8 * q;
        int a = jb0 + rr + rl;
        int srow = a > 2303 ? 2303 : a;
        gload_lds16(peb + ((size_t)(h * 2304 + srow)) * 64 + ((cch ^ rl) * 8),
                    &pering[((jb0 + rr) & 127) * 64]);
    }
    VDRAIN();
    __syncthreads();

    const int nt = ((i0 + 1343) >> 6) + 1;
    for (int t = 0; t < nt; ++t) {
        const int j0 = t * 64;
        const int jb = jb0 + j0;
        const bool more = (t + 1 < nt);

        // ---- QK & QP MFMA (read kbuf, pering) ----
        f32x4 qk[4], qp[5];
        #pragma unroll
        for (int nb = 0; nb < 4; ++nb) qk[nb] = z;
        #pragma unroll
        for (int f = 0; f < 5; ++f) qp[f] = z;
        #pragma unroll
        for (int ks = 0; ks < 2; ++ks) {
            #pragma unroll
            for (int nb = 0; nb < 4; ++nb) {
                int row = nb * 16 + lr;
                bf16x8 kb = *(const bf16x8*)&kbuf[row * 64 + (((4 * ks + lg) ^ (row & 7)) * 8)];
                qk[nb] = __builtin_amdgcn_mfma_f32_16x16x32_bf16(qf[ks], kb, qk[nb], 0, 0, 0);
            }
            #pragma unroll
            for (int f = 0; f < 5; ++f) {
                int rel = 48 - 16 * w + f * 16 + lr;
                int slot = (jb + rel) & 127;
                bf16x8 pb = *(const bf16x8*)&pering[slot * 64 + (((4 * ks + lg) ^ (slot & 7)) * 8)];
                qp[f] = __builtin_amdgcn_mfma_f32_16x16x32_bf16(qf[ks], pb, qp[f], 0, 0, 0);
            }
        }

        VDRAIN();   // retire own V(t) loads (issued after barrier C of t-1)
        SBAR();     // B: publishes V(t); certifies kbuf/pering reads of tile t

        if (more) { // stage K(t+1) and PE(t+1)
            const int j0n = j0 + 64;
            #pragma unroll
            for (int q = 0; q < 2; ++q) {
                int row = 16 * w + 8 * q + rl;
                gload_lds16(kvb + ((size_t)(b * 2304 + j0n + row)) * 2048 + h * 64 + ((cch ^ rl) * 8),
                            &kbuf[(16 * w + 8 * q) * 64]);
            }
            const int A0 = jb + 128;
            #pragma unroll
            for (int q = 0; q < 2; ++q) {
                int rr = A0 + 16 * w + 8 * q;
                int a = rr + rl;
                int srow = a > 2303 ? 2303 : a;
                gload_lds16(peb + ((size_t)(h * 2304 + srow)) * 64 + ((cch ^ rl) * 8),
                            &pering[(rr & 127) * 64]);
            }
        }

        // ---- main: mask + defer-max online softmax, shuffle qp gather ----
        const bool nomask = (j0 + 63 <= iw + 1280);
        #pragma unroll
        for (int jr = 0; jr < 4; ++jr) {
            const int r = lg * 4 + jr;
            const int ia = iw + r;
            const int src = (lane & 48) | ((lr + 15 - r) & 15);
            float rot0 = __shfl(qp[0][jr], src);
            float rot1 = __shfl(qp[1][jr], src);
            float rot2 = __shfl(qp[2][jr], src);
            float rot3 = __shfl(qp[3][jr], src);
            float rot4 = __shfl(qp[4][jr], src);
            const bool hi = (lr > r);
            float s0 = (qk[0][jr] + (hi ? rot1 : rot0)) * C2;
            float s1 = (qk[1][jr] + (hi ? rot2 : rot1)) * C2;
            float s2 = (qk[2][jr] + (hi ? rot3 : rot2)) * C2;
            float s3 = (qk[3][jr] + (hi ? rot4 : rot3)) * C2;
            if (!nomask) {
                s0 = (j0 + lr      <= ia + 1280) ? s0 : -1e30f;
                s1 = (j0 + lr + 16 <= ia + 1280) ? s1 : -1e30f;
                s2 = (j0 + lr + 32 <= ia + 1280) ? s2 : -1e30f;
                s3 = (j0 + lr + 48 <= ia + 1280) ? s3 : -1e30f;
            }
            float lm = fmaxf(fmaxf(s0, s1), fmaxf(s2, s3));
            if (__any(lm > mloc[jr] + 11.f)) {
                float tm = lm;
                #pragma unroll
                for (int mk = 1; mk < 16; mk <<= 1) tm = fmaxf(tm, __shfl_xor(tm, mk));
                float mn = fmaxf(mloc[jr], tm);
                float corr = exp2a(mloc[jr] - mn);
                mloc[jr] = mn; lloc[jr] *= corr;
                od[0][jr] *= corr; od[1][jr] *= corr; od[2][jr] *= corr; od[3][jr] *= corr;
            }
            float p0 = exp2a(s0 - mloc[jr]), p1 = exp2a(s1 - mloc[jr]);
            float p2 = exp2a(s2 - mloc[jr]), p3 = exp2a(s3 - mloc[jr]);
            unsigned pkA = cvtpk(p0, p1), pkB = cvtpk(p2, p3);
            u16* pw = &pls[w][r * 64];
            pw[pwidx[0]] = (u16)pkA; pw[pwidx[1]] = (u16)(pkA >> 16);
            pw[pwidx[2]] = (u16)pkB; pw[pwidx[3]] = (u16)(pkB >> 16);
            lloc[jr] += (p0 + p1) + (p2 + p3);
        }

        // ---- main PV MFMA ----
        #pragma unroll
        for (int ks = 0; ks < 2; ++ks) {
            bf16x8 pa = *(const bf16x8*)&pls[w][pridx[ks]];
            #pragma unroll
            for (int nb = 0; nb < 4; ++nb) {
                int d = nb * 16 + lr;
                bf16x8 vb = *(const bf16x8*)&vbuf[d * 64 + (((4 * ks + lg) ^ (d & 7)) * 8)];
                od[nb] = __builtin_amdgcn_mfma_f32_16x16x32_bf16(pa, vb, od[nb], 0, 0, 0);
            }
        }

        // ---- aux phase-0: kv rows 256..1279 == tiles 4..19 ----
        if (t >= 4 && t <= 19) {
            #pragma unroll
            for (int jr = 0; jr < 4; ++jr) {
                const int r = lg * 4 + jr;
                float s0 = qk[0][jr] * C2, s1 = qk[1][jr] * C2;
                float s2 = qk[2][jr] * C2, s3 = qk[3][jr] * C2;
                float lm = fmaxf(fmaxf(s0, s1), fmaxf(s2, s3));
                if (__any(lm > ml2[jr] + 11.f)) {
                    float tm = lm;
                    #pragma unroll
                    for (int mk = 1; mk < 16; mk <<= 1) tm = fmaxf(tm, __shfl_xor(tm, mk));
                    float mn = fmaxf(ml2[jr], tm);
                    float corr = exp2a(ml2[jr] - mn);
                    ml2[jr] = mn; ll2[jr] *= corr;
                    od2[0][jr] *= corr; od2[1][jr] *= corr; od2[2][jr] *= corr; od2[3][jr] *= corr;
                }
                float p0 = exp2a(s0 - ml2[jr]), p1 = exp2a(s1 - ml2[jr]);
                float p2 = exp2a(s2 - ml2[jr]), p3 = exp2a(s3 - ml2[jr]);
                unsigned pkA = cvtpk(p0, p1), pkB = cvtpk(p2, p3);
                u16* pw = &pls[w][r * 64];
                pw[pwidx[0]] = (u16)pkA; pw[pwidx[1]] = (u16)(pkA >> 16);
                pw[pwidx[2]] = (u16)pkB; pw[pwidx[3]] = (u16)(pkB >> 16);
                ll2[jr] += (p0 + p1) + (p2 + p3);
            }
            #pragma unroll
            for (int ks = 0; ks < 2; ++ks) {
                bf16x8 pa = *(const bf16x8*)&pls[w][pridx[ks]];
                #pragma unroll
                for (int nb = 0; nb < 4; ++nb) {
                    int d = nb * 16 + lr;
                    bf16x8 vb = *(const bf16x8*)&vbuf[d * 64 + (((4 * ks + lg) ^ (d & 7)) * 8)];
                    od2[nb] = __builtin_amdgcn_mfma_f32_16x16x32_bf16(pa, vb, od2[nb], 0, 0, 0);
                }
            }
        }

        VDRAIN();   // retire own K(t+1)/PE(t+1) loads
        SBAR();     // C: publishes kbuf=K(t+1), pering; certifies vbuf/pls reads

        if (more) { // stage V(t+1)
            const int j0n = j0 + 64;
            #pragma unroll
            for (int q = 0; q < 2; ++q) {
                int row = 16 * w + 8 * q + rl;
                gload_lds16(vt + ((size_t)(bh * 64 + row)) * 2304 + j0n + ((cch ^ rl) * 8),
                            &vbuf[(16 * w + 8 * q) * 64]);
            }
        }
    }

    // ---- main epilogue ----
    #pragma unroll
    for (int jr = 0; jr < 4; ++jr) {
        float l = lloc[jr];
        #pragma unroll
        for (int mk = 1; mk < 16; mk <<= 1) l += __shfl_xor(l, mk);
        float inv = 1.f / l;
        int ia = iw + lg * 4 + jr;
        #pragma unroll
        for (int nb = 0; nb < 4; ++nb)
            outb[((size_t)(b * 1024 + ia)) * 1024 + h * 64 + nb * 16 + lr] =
                f2b(od[nb][jr] * inv);
    }
    // ---- aux phase-0 epilogue ----
    #pragma unroll
    for (int jr = 0; jr < 4; ++jr) {
        float l = ll2[jr];
        #pragma unroll
        for (int mk = 1; mk < 16; mk <<= 1) l += __shfl_xor(l, mk);
        float inv = 1.f / l;
        int ig = i0 + 16 * w + lg * 4 + jr;
        #pragma unroll
        for (int nb = 0; nb < 4; ++nb)
            auxo[((size_t)(bh * 1024 + ig)) * 64 + nb * 16 + lr] = od2[nb][jr] * inv;
    }
}

// ---------------- aux phase-1 (compressed KV) + squared diff ----------------
__global__ __launch_bounds__(256) void attn_aux_diff(
    const u16* __restrict__ qb, const u16* __restrict__ ckcv,
    const u16* __restrict__ cvt, const float* __restrict__ auxo,
    float* __restrict__ acc)
{
    __shared__ u16 kbuf[64 * 64];
    __shared__ u16 vbuf[64 * 64];
    __shared__ u16 pls[4][1024];
    __shared__ float red[4];

    const int tid = threadIdx.x;
    const int w = tid >> 6, lane = tid & 63;
    const int lr = lane & 15, lg = lane >> 4;
    const int rl = lane >> 3, cch = lane & 7;
    const int bh = blockIdx.y, b = bh >> 4, h = bh & 15;
    const int i0 = blockIdx.x * 64;
    const int iw = i0 + 16 * w;

    const int lrh = lr >> 3, lrm = lr & 7;
    int pwidx[4], pridx[2];
    #pragma unroll
    for (int nb = 0; nb < 4; ++nb)
        pwidx[nb] = (((nb * 2 + lrh) ^ (lg * 2)) * 8) + lrm;
    #pragma unroll
    for (int ks = 0; ks < 2; ++ks)
        pridx[ks] = lr * 64 + (((ks * 4 + lg) ^ ((lr >> 2) * 2)) * 8);

    const u16* kbase = ckcv + ((size_t)(b * 256)) * 2048 + h * 64;
    const u16* vbase = cvt + ((size_t)(bh * 64)) * 256;

    bf16x8 qf[2];
    #pragma unroll
    for (int ks = 0; ks < 2; ++ks)
        qf[ks] = *(const bf16x8*)(qb + ((size_t)(b * 1024 + iw + lr)) * 1024
                                  + h * 64 + ks * 32 + lg * 8);

    const f32x4 z = {0.f, 0.f, 0.f, 0.f};
    f32x4 od[4];
    float mloc[4], lloc[4];
    #pragma unroll
    for (int nb = 0; nb < 4; ++nb) od[nb] = z;
    #pragma unroll
    for (int jr = 0; jr < 4; ++jr) { mloc[jr] = -1e30f; lloc[jr] = 0.f; }

    for (int t = 0; t < 4; ++t) {
        const int j0 = t * 64;
        __syncthreads();
        #pragma unroll
        for (int q = 0; q < 2; ++q) {
            int row = 16 * w + 8 * q + rl;
            gload_lds16(kbase + (size_t)(j0 + row) * 2048 + ((cch ^ rl) * 8),
                        &kbuf[(16 * w + 8 * q) * 64]);
            gload_lds16(vbase + (size_t)row * 256 + j0 + ((cch ^ rl) * 8),
                        &vbuf[(16 * w + 8 * q) * 64]);
        }
        __syncthreads();

        f32x4 qk[4];
        #pragma unroll
        for (int nb = 0; nb < 4; ++nb) qk[nb] = z;
        #pragma unroll
        for (int ks = 0; ks < 2; ++ks)
            #pragma unroll
            for (int nb = 0; nb < 4; ++nb) {
                int row = nb * 16 + lr;
                bf16x8 kb = *(const bf16x8*)&kbuf[row * 64 + (((4 * ks + lg) ^ (row & 7)) * 8)];
                qk[nb] = __builtin_amdgcn_mfma_f32_16x16x32_bf16(qf[ks], kb, qk[nb], 0, 0, 0);
            }

        #pragma unroll
        for (int jr = 0; jr < 4; ++jr) {
            const int r = lg * 4 + jr;
            float s0 = qk[0][jr] * C2, s1 = qk[1][jr] * C2;
            float s2 = qk[2][jr] * C2, s3 = qk[3][jr] * C2;
            float lm = fmaxf(fmaxf(s0, s1), fmaxf(s2, s3));
            if (__any(lm > mloc[jr] + 11.f)) {
                float tm = lm;
                #pragma unroll
                for (int mk = 1; mk < 16; mk <<= 1) tm = fmaxf(tm, __shfl_xor(tm, mk));
                float mn = fmaxf(mloc[jr], tm);
                float corr = exp2a(mloc[jr] - mn);
                mloc[jr] = mn; lloc[jr] *= corr;
                od[0][jr] *= corr; od[1][jr] *= corr; od[2][jr] *= corr; od[3][jr] *= corr;
            }
            float p0 = exp2a(s0 - mloc[jr]), p1 = exp2a(s1 - mloc[jr]);
            float p2 = exp2a(s2 - mloc[jr]), p3 = exp2a(s3 - mloc[jr]);
            unsigned pkA = cvtpk(p0, p1), pkB = cvtpk(p2, p3);
            u16* pw = &pls[w][r * 64];
            pw[pwidx[0]] = (u16)pkA; pw[pwidx[1]] = (u16)(pkA >> 16);
            pw[pwidx[2]] = (u16)pkB; pw[pwidx[3]] = (u16)(pkB >> 16);
            lloc[jr] += (p0 + p1) + (p2 + p3);
        }

        #pragma unroll
        for (int ks = 0; ks < 2; ++ks) {
            bf16x8 pa = *(const bf16x8*)&pls[w][pridx[ks]];
            #pragma unroll
            for (int nb = 0; nb < 4; ++nb) {
                int d = nb * 16 + lr;
                bf16x8 vb = *(const bf16x8*)&vbuf[d * 64 + (((4 * ks + lg) ^ (d & 7)) * 8)];
                od[nb] = __builtin_amdgcn_mfma_f32_16x16x32_bf16(pa, vb, od[nb], 0, 0, 0);
            }
        }
    }

    float local = 0.f;
    #pragma unroll
    for (int jr = 0; jr < 4; ++jr) {
        float l = lloc[jr];
        #pragma unroll
        for (int mk = 1; mk < 16; mk <<= 1) l += __shfl_xor(l, mk);
        float inv = 1.f / l;
        int ig = i0 + 16 * w + lg * 4 + jr;
        #pragma unroll
        for (int nb = 0; nb < 4; ++nb) {
            float o2 = od[nb][jr] * inv;
            float o1 = auxo[((size_t)(bh * 1024 + ig)) * 64 + nb * 16 + lr];
            float d = o1 - o2;
            local += d * d;
        }
    }
    #pragma unroll
    for (int mk = 1; mk < 64; mk <<= 1) local += __shfl_xor(local, mk);
    if (lane == 0) red[w] = local;
    __syncthreads();
    if (tid == 0) atomicAdd(acc, red[0] + red[1] + red[2] + red[3]);
}

__global__ void finish_aux(const float* __restrict__ acc, float* __restrict__ out)
{
    out[0] = acc[0] * (1.0f / 4194304.0f);
}

// ---------------- launch ----------------
extern "C" void kernel_launch(void* const* d_in, const int* in_sizes, int n_in,
                              void* d_out, int out_size, void* d_ws, size_t ws_size,
                              hipStream_t stream)
{
    const float* x     = (const float*)d_in[0];
    const float* mem   = (const float*)d_in[1];
    const float* cmem  = (const float*)d_in[2];
    const float* pos   = (const float*)d_in[3];
    const float* Wq    = (const float*)d_in[5];
    const float* Wkv   = (const float*)d_in[6];
    const float* Wout  = (const float*)d_in[7];
    const float* bout  = (const float*)d_in[8];
    const float* convw = (const float*)d_in[9];
    const float* convb = (const float*)d_in[10];

    float* out      = (float*)d_out;
    float* logits   = out;
    float* new_mem  = out + 4194304;
    float* new_cmem = out + 8388608;
    float* aux_out  = out + 9437184;

    char* p = (char*)d_ws;
    u16* kvb   = (u16*)p; p += (size_t)9216 * 2048 * 2;
    u16* qb    = (u16*)p; p += (size_t)4096 * 1024 * 2;
    u16* kvin  = (u16*)p; p += (size_t)9216 * 1024 * 2;   // reused as vt after kv GEMM
    u16* wkvt  = (u16*)p; p += (size_t)2048 * 1024 * 2;
    u16* wqt   = (u16*)p; p += (size_t)1024 * 1024 * 2;
    u16* woutt = (u16*)p; p += (size_t)1024 * 1024 * 2;
    u16* w2t   = (u16*)p; p += (size_t)1024 * 4096 * 2;   // reused as cvt after compress GEMM
    u16* peb   = (u16*)p; p += (size_t)16 * 2304 * 64 * 2;
    u16* xb    = (u16*)p; p += (size_t)4096 * 1024 * 2;   // reused (with memb) as auxo
    u16* memb  = (u16*)p; p += (size_t)4096 * 1024 * 2;
    u16* cmpb  = (u16*)p; p += (size_t)1024 * 1024 * 2;
    u16* ckcvb = (u16*)p; p += (size_t)1024 * 2048 * 2;
    u16* aob   = (u16*)p; p += (size_t)4096 * 1024 * 2;
    float* acc = (float*)p;
    u16* vt   = kvin;          // 4096 x 2304 u16, exact fit
    u16* cvt  = w2t;           // 4096 x 256 u16, fits
    float* auxo = (float*)xb;  // 4,194,304 f32 == xb+memb region exactly

    hipMemcpyAsync(new_mem, x, (size_t)4194304 * sizeof(float),
                   hipMemcpyDeviceToDevice, stream);

    cvt_bf16<<<4096, 256, 0, stream>>>(x, xb, 1048576);
    cvt_bf16<<<4096, 256, 0, stream>>>(mem, memb, 1048576);
    cvt_bf16<<<2304, 256, 0, stream>>>(pos, peb, 589824);
    concat_bf16<<<9216, 256, 0, stream>>>(x, mem, cmem, kvin);
    transpose_bf16<<<dim3(64, 32), 256, 0, stream>>>(Wkv, wkvt, 1024, 2048);
    transpose_bf16<<<dim3(32, 32), 256, 0, stream>>>(Wq, wqt, 1024, 1024);
    transpose_bf16<<<dim3(32, 32), 256, 0, stream>>>(Wout, woutt, 1024, 1024);
    w2t_bf16<<<16384, 256, 0, stream>>>(convw, w2t);

    gemm_bf16<<<dim3(16, 72), 256, 0, stream>>>(kvin, wkvt, nullptr, nullptr, kvb, 9216, 2048, 1024);
    transpose_v<<<dim3(36, 64), 256, 0, stream>>>(kvb, 2304, vt);
    gemm_bf16<<<dim3(8, 32), 256, 0, stream>>>(xb, wqt, nullptr, nullptr, qb, 4096, 1024, 1024);
    gemm_bf16<<<dim3(8, 8), 256, 0, stream>>>(memb, w2t, convb, new_cmem, cmpb, 1024, 1024, 4096);
    gemm_bf16<<<dim3(16, 8), 256, 0, stream>>>(cmpb, wkvt, nullptr, nullptr, ckcvb, 1024, 2048, 1024);
    transpose_v<<<dim3(4, 64), 256, 0, stream>>>(ckcvb, 256, cvt);

    // xb/memb dead from here -> auxo overlays them
    attn_main_fused<<<dim3(16, 64), 256, 0, stream>>>(qb, kvb, vt, peb, aob, auxo);
    gemm_bf16<<<dim3(8, 32), 256, 0, stream>>>(aob, woutt, bout, logits, nullptr, 4096, 1024, 1024);

    hipMemsetAsync(acc, 0, sizeof(float), stream);
    attn_aux_diff<<<dim3(16, 64), 256, 0, stream>>>(qb, ckcvb, cvt, auxo, acc);
    finish_aux<<<1, 1, 0, stream>>>(acc, aux_out);
}

// Round 6
// 533.669 us; speedup vs baseline: 1.5905x; 1.5905x over previous
//
#include <hip/hip_runtime.h>
#include <hip/hip_bf16.h>
#include <cstddef>

typedef unsigned short u16;
typedef __attribute__((ext_vector_type(8))) short bf16x8;
typedef __attribute__((ext_vector_type(4))) float f32x4;

#define C2 0.18033688011112042f   // 0.125 * log2(e)

__device__ __forceinline__ u16 f2b(float f) {
    unsigned u = __builtin_bit_cast(unsigned, f);
    unsigned r = (u + 0x7FFF + ((u >> 16) & 1)) >> 16;
    return (u16)r;
}

__device__ __forceinline__ float exp2a(float x) {
    float r; asm("v_exp_f32 %0, %1" : "=v"(r) : "v"(x)); return r;
}

__device__ __forceinline__ unsigned cvtpk(float lo, float hi) {
    unsigned r; asm("v_cvt_pk_bf16_f32 %0, %1, %2" : "=v"(r) : "v"(lo), "v"(hi));
    return r;
}

__device__ __forceinline__ void gload_lds16(const void* g, void* l) {
    __builtin_amdgcn_global_load_lds(
        (const __attribute__((address_space(1))) unsigned int*)g,
        (__attribute__((address_space(3))) unsigned int*)l, 16, 0, 0);
}

#define VDRAIN() asm volatile("s_waitcnt vmcnt(0)" ::: "memory")
#define SBAR() do { __builtin_amdgcn_sched_barrier(0); __builtin_amdgcn_s_barrier(); } while (0)

// ---------------- elementwise fp32 -> bf16 ----------------
__global__ __launch_bounds__(256) void cvt_bf16(const float* __restrict__ in,
                                                u16* __restrict__ out, int n4)
{
    int i = blockIdx.x * 256 + threadIdx.x;
    if (i >= n4) return;
    float4 v = ((const float4*)in)[i];
    union { u16 s[4]; uint2 u; } pk;
    pk.s[0] = f2b(v.x); pk.s[1] = f2b(v.y); pk.s[2] = f2b(v.z); pk.s[3] = f2b(v.w);
    ((uint2*)out)[i] = pk.u;
}

// ---------------- kv_input concat (bf16) ----------------
__global__ __launch_bounds__(256) void concat_bf16(
    const float* __restrict__ x, const float* __restrict__ mem,
    const float* __restrict__ cmem, u16* __restrict__ out)
{
    int rowg = blockIdx.x;               // 0..9215
    int b = rowg / 2304, rr = rowg % 2304;
    const float* src = (rr < 256)  ? cmem + ((size_t)b * 256 + rr) * 1024
                     : (rr < 1280) ? mem  + ((size_t)b * 1024 + (rr - 256)) * 1024
                                   : x    + ((size_t)b * 1024 + (rr - 1280)) * 1024;
    float4 v = ((const float4*)src)[threadIdx.x];
    union { u16 s[4]; uint2 u; } pk;
    pk.s[0] = f2b(v.x); pk.s[1] = f2b(v.y); pk.s[2] = f2b(v.z); pk.s[3] = f2b(v.w);
    ((uint2*)(out + (size_t)rowg * 1024))[threadIdx.x] = pk.u;
}

// ---------------- transpose fp32 [K][N] -> bf16 [N][K] ----------------
__global__ __launch_bounds__(256) void transpose_bf16(
    const float* __restrict__ in, u16* __restrict__ out, int K, int N)
{
    __shared__ float t[32][33];
    int k0 = blockIdx.y * 32, n0 = blockIdx.x * 32;
    int tx = threadIdx.x & 31, ty = threadIdx.x >> 5;
    #pragma unroll
    for (int p = 0; p < 4; ++p)
        t[ty + 8 * p][tx] = in[(size_t)(k0 + ty + 8 * p) * N + n0 + tx];
    __syncthreads();
    #pragma unroll
    for (int p = 0; p < 4; ++p)
        out[(size_t)(n0 + ty + 8 * p) * K + k0 + tx] = f2b(t[tx][ty + 8 * p]);
}

// ---------------- conv_w[o,i,r] -> W2t[o][r*1024+i] bf16 ----------------
__global__ __launch_bounds__(256) void w2t_bf16(const float* __restrict__ cw,
                                                u16* __restrict__ out)
{
    size_t idx = (size_t)blockIdx.x * 256 + threadIdx.x;  // 1024*4096
    int o = (int)(idx >> 12), k = (int)(idx & 4095);
    out[idx] = f2b(cw[(size_t)o * 4096 + (k & 1023) * 4 + (k >> 10)]);
}

// ---------------- V half of [rows][2048] -> Vt[(bh*64+d)][rows] ----------------
__global__ __launch_bounds__(256) void transpose_v(
    const u16* __restrict__ src, int R, u16* __restrict__ dst)
{
    __shared__ u16 t[64 * 65];
    int bh = blockIdx.y, b = bh >> 4, h = bh & 15;
    int j0 = blockIdx.x * 64;
    int tid = threadIdx.x;
    #pragma unroll
    for (int p = 0; p < 2; ++p) {
        int idx = tid + p * 256;
        int j = idx >> 3, c = idx & 7;
        uint4 v = *(const uint4*)(src + ((size_t)(b * R + j0 + j)) * 2048 + 1024 + h * 64 + c * 8);
        const u16* vv = (const u16*)&v;
        #pragma unroll
        for (int u2 = 0; u2 < 8; ++u2) t[j * 65 + c * 8 + u2] = vv[u2];
    }
    __syncthreads();
    #pragma unroll
    for (int p = 0; p < 2; ++p) {
        int idx = tid + p * 256;
        int jc = idx & 7, d = idx >> 3;
        union { u16 s[8]; uint4 u; } pk;
        #pragma unroll
        for (int u2 = 0; u2 < 8; ++u2) pk.s[u2] = t[(jc * 8 + u2) * 65 + d];
        *(uint4*)(dst + ((size_t)(bh * 64 + d)) * (size_t)R + j0 + jc * 8) = pk.u;
    }
}

// ---------------- bf16 MFMA GEMM: C[M,N] = A[M,K] @ Bt[N,K]^T (+bias) ----------------
__global__ __launch_bounds__(256) void gemm_bf16(
    const u16* __restrict__ A, const u16* __restrict__ Bt,
    const float* __restrict__ bias, float* __restrict__ Cf,
    u16* __restrict__ Cb, int M, int N, int K)
{
    __shared__ u16 Al[128 * 32];
    __shared__ u16 Bl[128 * 32];
    const int tid = threadIdx.x, w = tid >> 6, lane = tid & 63;
    const int lr = lane & 15, lg = lane >> 4;
    const int bm0 = blockIdx.y * 128, bn0 = blockIdx.x * 128;
    const int wr = (w >> 1) * 64, wc = (w & 1) * 64;

    f32x4 acc[4][4];
    const f32x4 z = {0.f, 0.f, 0.f, 0.f};
    #pragma unroll
    for (int mb = 0; mb < 4; ++mb)
        #pragma unroll
        for (int nb = 0; nb < 4; ++nb) acc[mb][nb] = z;

    for (int k0 = 0; k0 < K; k0 += 32) {
        __syncthreads();
        #pragma unroll
        for (int q = 0; q < 2; ++q) {
            int chunk = w * 2 + q;
            int row = chunk * 16 + (lane >> 2);
            int sg = (lane & 3) * 8;
            gload_lds16(A + (size_t)(bm0 + row) * K + k0 + sg, &Al[chunk * 512]);
            gload_lds16(Bt + (size_t)(bn0 + row) * K + k0 + sg, &Bl[chunk * 512]);
        }
        __syncthreads();
        bf16x8 af[4], bf[4];
        #pragma unroll
        for (int mb = 0; mb < 4; ++mb)
            af[mb] = *(const bf16x8*)&Al[(wr + mb * 16 + lr) * 32 + lg * 8];
        #pragma unroll
        for (int nb = 0; nb < 4; ++nb)
            bf[nb] = *(const bf16x8*)&Bl[(wc + nb * 16 + lr) * 32 + lg * 8];
        #pragma unroll
        for (int mb = 0; mb < 4; ++mb)
            #pragma unroll
            for (int nb = 0; nb < 4; ++nb)
                acc[mb][nb] = __builtin_amdgcn_mfma_f32_16x16x32_bf16(
                    af[mb], bf[nb], acc[mb][nb], 0, 0, 0);
    }

    #pragma unroll
    for (int mb = 0; mb < 4; ++mb)
        #pragma unroll
        for (int nb = 0; nb < 4; ++nb)
            #pragma unroll
            for (int jr = 0; jr < 4; ++jr) {
                int row = bm0 + wr + mb * 16 + lg * 4 + jr;
                int col = bn0 + wc + nb * 16 + lr;
                float v = acc[mb][nb][jr] + (bias ? bias[col] : 0.f);
                if (Cf) Cf[(size_t)row * N + col] = v;
                if (Cb) Cb[(size_t)row * N + col] = f2b(v);
            }
}

// ---------------- fused main attention + aux phase-0 ----------------
// LDS 40960 B; natural VGPR allocation (no min-wave cap -> no spill).
__global__ __launch_bounds__(256) void attn_main_fused(
    const u16* __restrict__ qb,    // (4,1024,1024) bf16
    const u16* __restrict__ kvb,   // (4,2304,2048) bf16 k|v
    const u16* __restrict__ vt,    // (64bh*64d, 2304) bf16  V^T
    const u16* __restrict__ peb,   // (16,2304,64) bf16
    u16* __restrict__ outb,        // (4,1024,1024) bf16
    float* __restrict__ auxo)      // (64bh,1024,64) fp32 aux phase-0 out
{
    __shared__ u16 kbuf[64 * 64];      // 8 KB
    __shared__ u16 vbuf[64 * 64];      // 8 KB  [d][j-chunks] swizzled
    __shared__ u16 pering[128 * 64];   // 16 KB ring
    __shared__ u16 pls[4][1024];       // 8 KB, XOR-swizzled P

    const int tid = threadIdx.x;
    const int w = tid >> 6, lane = tid & 63;
    const int lr = lane & 15, lg = lane >> 4;
    const int rl = lane >> 3, cch = lane & 7;
    const int bh = blockIdx.y, b = bh >> 4, h = bh & 15;
    const int i0 = blockIdx.x * 64;
    const int iw = i0 + 16 * w;
    const int jb0 = 960 - i0;

    // per-thread constant pls indices
    const int lrh = lr >> 3, lrm = lr & 7;
    int pwidx[4], pridx[2];
    #pragma unroll
    for (int nb = 0; nb < 4; ++nb)
        pwidx[nb] = (((nb * 2 + lrh) ^ (lg * 2)) * 8) + lrm;
    #pragma unroll
    for (int ks = 0; ks < 2; ++ks)
        pridx[ks] = lr * 64 + (((ks * 4 + lg) ^ ((lr >> 2) * 2)) * 8);

    bf16x8 qf[2];
    #pragma unroll
    for (int ks = 0; ks < 2; ++ks)
        qf[ks] = *(const bf16x8*)(qb + ((size_t)(b * 1024 + iw + lr)) * 1024
                                  + h * 64 + ks * 32 + lg * 8);

    const f32x4 z = {0.f, 0.f, 0.f, 0.f};
    f32x4 od[4], od2[4];
    float mloc[4], lloc[4], ml2[4], ll2[4];
    #pragma unroll
    for (int nb = 0; nb < 4; ++nb) { od[nb] = z; od2[nb] = z; }
    #pragma unroll
    for (int jr = 0; jr < 4; ++jr) {
        mloc[jr] = -1e30f; lloc[jr] = 0.f;
        ml2[jr] = -1e30f; ll2[jr] = 0.f;
    }

    // ---- prologue: K(0), V(0), full 128-row PE band ----
    #pragma unroll
    for (int q = 0; q < 2; ++q) {
        int row = 16 * w + 8 * q + rl;
        gload_lds16(kvb + ((size_t)(b * 2304 + row)) * 2048 + h * 64 + ((cch ^ rl) * 8),
                    &kbuf[(16 * w + 8 * q) * 64]);
        gload_lds16(vt + ((size_t)(bh * 64 + row)) * 2304 + ((cch ^ rl) * 8),
                    &vbuf[(16 * w + 8 * q) * 64]);
    }
    #pragma unroll
    for (int q = 0; q < 4; ++q) {
        int rr = 32 * w + 8 * q;
        int a = jb0 + rr + rl;
        int srow = a > 2303 ? 2303 : a;
        gload_lds16(peb + ((size_t)(h * 2304 + srow)) * 64 + ((cch ^ rl) * 8),
                    &pering[((jb0 + rr) & 127) * 64]);
    }
    VDRAIN();
    __syncthreads();

    const int nt = ((i0 + 1343) >> 6) + 1;
    for (int t = 0; t < nt; ++t) {
        const int j0 = t * 64;
        const int jb = jb0 + j0;
        const bool more = (t + 1 < nt);

        // ---- QK & QP MFMA (read kbuf, pering) ----
        f32x4 qk[4], qp[5];
        #pragma unroll
        for (int nb = 0; nb < 4; ++nb) qk[nb] = z;
        #pragma unroll
        for (int f = 0; f < 5; ++f) qp[f] = z;
        #pragma unroll
        for (int ks = 0; ks < 2; ++ks) {
            #pragma unroll
            for (int nb = 0; nb < 4; ++nb) {
                int row = nb * 16 + lr;
                bf16x8 kb = *(const bf16x8*)&kbuf[row * 64 + (((4 * ks + lg) ^ (row & 7)) * 8)];
                qk[nb] = __builtin_amdgcn_mfma_f32_16x16x32_bf16(qf[ks], kb, qk[nb], 0, 0, 0);
            }
            #pragma unroll
            for (int f = 0; f < 5; ++f) {
                int rel = 48 - 16 * w + f * 16 + lr;
                int slot = (jb + rel) & 127;
                bf16x8 pb = *(const bf16x8*)&pering[slot * 64 + (((4 * ks + lg) ^ (slot & 7)) * 8)];
                qp[f] = __builtin_amdgcn_mfma_f32_16x16x32_bf16(qf[ks], pb, qp[f], 0, 0, 0);
            }
        }

        VDRAIN();   // retire own V(t) loads (issued after barrier C of t-1)
        SBAR();     // B: publishes V(t); certifies kbuf/pering reads of tile t

        if (more) { // stage K(t+1) and PE(t+1)
            const int j0n = j0 + 64;
            #pragma unroll
            for (int q = 0; q < 2; ++q) {
                int row = 16 * w + 8 * q + rl;
                gload_lds16(kvb + ((size_t)(b * 2304 + j0n + row)) * 2048 + h * 64 + ((cch ^ rl) * 8),
                            &kbuf[(16 * w + 8 * q) * 64]);
            }
            const int A0 = jb + 128;
            #pragma unroll
            for (int q = 0; q < 2; ++q) {
                int rr = A0 + 16 * w + 8 * q;
                int a = rr + rl;
                int srow = a > 2303 ? 2303 : a;
                gload_lds16(peb + ((size_t)(h * 2304 + srow)) * 64 + ((cch ^ rl) * 8),
                            &pering[(rr & 127) * 64]);
            }
        }

        // ---- main: mask + defer-max online softmax, shuffle qp gather ----
        const bool nomask = (j0 + 63 <= iw + 1280);
        #pragma unroll
        for (int jr = 0; jr < 4; ++jr) {
            const int r = lg * 4 + jr;
            const int ia = iw + r;
            const int src = (lane & 48) | ((lr + 15 - r) & 15);
            float rot0 = __shfl(qp[0][jr], src);
            float rot1 = __shfl(qp[1][jr], src);
            float rot2 = __shfl(qp[2][jr], src);
            float rot3 = __shfl(qp[3][jr], src);
            float rot4 = __shfl(qp[4][jr], src);
            const bool hi = (lr > r);
            float s0 = (qk[0][jr] + (hi ? rot1 : rot0)) * C2;
            float s1 = (qk[1][jr] + (hi ? rot2 : rot1)) * C2;
            float s2 = (qk[2][jr] + (hi ? rot3 : rot2)) * C2;
            float s3 = (qk[3][jr] + (hi ? rot4 : rot3)) * C2;
            if (!nomask) {
                s0 = (j0 + lr      <= ia + 1280) ? s0 : -1e30f;
                s1 = (j0 + lr + 16 <= ia + 1280) ? s1 : -1e30f;
                s2 = (j0 + lr + 32 <= ia + 1280) ? s2 : -1e30f;
                s3 = (j0 + lr + 48 <= ia + 1280) ? s3 : -1e30f;
            }
            float lm = fmaxf(fmaxf(s0, s1), fmaxf(s2, s3));
            if (__any(lm > mloc[jr] + 11.f)) {
                float tm = lm;
                #pragma unroll
                for (int mk = 1; mk < 16; mk <<= 1) tm = fmaxf(tm, __shfl_xor(tm, mk));
                float mn = fmaxf(mloc[jr], tm);
                float corr = exp2a(mloc[jr] - mn);
                mloc[jr] = mn; lloc[jr] *= corr;
                od[0][jr] *= corr; od[1][jr] *= corr; od[2][jr] *= corr; od[3][jr] *= corr;
            }
            float p0 = exp2a(s0 - mloc[jr]), p1 = exp2a(s1 - mloc[jr]);
            float p2 = exp2a(s2 - mloc[jr]), p3 = exp2a(s3 - mloc[jr]);
            unsigned pkA = cvtpk(p0, p1), pkB = cvtpk(p2, p3);
            u16* pw = &pls[w][r * 64];
            pw[pwidx[0]] = (u16)pkA; pw[pwidx[1]] = (u16)(pkA >> 16);
            pw[pwidx[2]] = (u16)pkB; pw[pwidx[3]] = (u16)(pkB >> 16);
            lloc[jr] += (p0 + p1) + (p2 + p3);
        }

        // ---- main PV MFMA ----
        #pragma unroll
        for (int ks = 0; ks < 2; ++ks) {
            bf16x8 pa = *(const bf16x8*)&pls[w][pridx[ks]];
            #pragma unroll
            for (int nb = 0; nb < 4; ++nb) {
                int d = nb * 16 + lr;
                bf16x8 vb = *(const bf16x8*)&vbuf[d * 64 + (((4 * ks + lg) ^ (d & 7)) * 8)];
                od[nb] = __builtin_amdgcn_mfma_f32_16x16x32_bf16(pa, vb, od[nb], 0, 0, 0);
            }
        }

        // ---- aux phase-0: kv rows 256..1279 == tiles 4..19 ----
        if (t >= 4 && t <= 19) {
            #pragma unroll
            for (int jr = 0; jr < 4; ++jr) {
                const int r = lg * 4 + jr;
                float s0 = qk[0][jr] * C2, s1 = qk[1][jr] * C2;
                float s2 = qk[2][jr] * C2, s3 = qk[3][jr] * C2;
                float lm = fmaxf(fmaxf(s0, s1), fmaxf(s2, s3));
                if (__any(lm > ml2[jr] + 11.f)) {
                    float tm = lm;
                    #pragma unroll
                    for (int mk = 1; mk < 16; mk <<= 1) tm = fmaxf(tm, __shfl_xor(tm, mk));
                    float mn = fmaxf(ml2[jr], tm);
                    float corr = exp2a(ml2[jr] - mn);
                    ml2[jr] = mn; ll2[jr] *= corr;
                    od2[0][jr] *= corr; od2[1][jr] *= corr; od2[2][jr] *= corr; od2[3][jr] *= corr;
                }
                float p0 = exp2a(s0 - ml2[jr]), p1 = exp2a(s1 - ml2[jr]);
                float p2 = exp2a(s2 - ml2[jr]), p3 = exp2a(s3 - ml2[jr]);
                unsigned pkA = cvtpk(p0, p1), pkB = cvtpk(p2, p3);
                u16* pw = &pls[w][r * 64];
                pw[pwidx[0]] = (u16)pkA; pw[pwidx[1]] = (u16)(pkA >> 16);
                pw[pwidx[2]] = (u16)pkB; pw[pwidx[3]] = (u16)(pkB >> 16);
                ll2[jr] += (p0 + p1) + (p2 + p3);
            }
            #pragma unroll
            for (int ks = 0; ks < 2; ++ks) {
                bf16x8 pa = *(const bf16x8*)&pls[w][pridx[ks]];
                #pragma unroll
                for (int nb = 0; nb < 4; ++nb) {
                    int d = nb * 16 + lr;
                    bf16x8 vb = *(const bf16x8*)&vbuf[d * 64 + (((4 * ks + lg) ^ (d & 7)) * 8)];
                    od2[nb] = __builtin_amdgcn_mfma_f32_16x16x32_bf16(pa, vb, od2[nb], 0, 0, 0);
                }
            }
        }

        VDRAIN();   // retire own K(t+1)/PE(t+1) loads
        SBAR();     // C: publishes kbuf=K(t+1), pering; certifies vbuf/pls reads

        if (more) { // stage V(t+1)
            const int j0n = j0 + 64;
            #pragma unroll
            for (int q = 0; q < 2; ++q) {
                int row = 16 * w + 8 * q + rl;
                gload_lds16(vt + ((size_t)(bh * 64 + row)) * 2304 + j0n + ((cch ^ rl) * 8),
                            &vbuf[(16 * w + 8 * q) * 64]);
            }
        }
    }

    // ---- main epilogue ----
    #pragma unroll
    for (int jr = 0; jr < 4; ++jr) {
        float l = lloc[jr];
        #pragma unroll
        for (int mk = 1; mk < 16; mk <<= 1) l += __shfl_xor(l, mk);
        float inv = 1.f / l;
        int ia = iw + lg * 4 + jr;
        #pragma unroll
        for (int nb = 0; nb < 4; ++nb)
            outb[((size_t)(b * 1024 + ia)) * 1024 + h * 64 + nb * 16 + lr] =
                f2b(od[nb][jr] * inv);
    }
    // ---- aux phase-0 epilogue ----
    #pragma unroll
    for (int jr = 0; jr < 4; ++jr) {
        float l = ll2[jr];
        #pragma unroll
        for (int mk = 1; mk < 16; mk <<= 1) l += __shfl_xor(l, mk);
        float inv = 1.f / l;
        int ig = i0 + 16 * w + lg * 4 + jr;
        #pragma unroll
        for (int nb = 0; nb < 4; ++nb)
            auxo[((size_t)(bh * 1024 + ig)) * 64 + nb * 16 + lr] = od2[nb][jr] * inv;
    }
}

// ---------------- aux phase-1 (compressed KV) + squared diff ----------------
__global__ __launch_bounds__(256) void attn_aux_diff(
    const u16* __restrict__ qb, const u16* __restrict__ ckcv,
    const u16* __restrict__ cvt, const float* __restrict__ auxo,
    float* __restrict__ acc)
{
    __shared__ u16 kbuf[64 * 64];
    __shared__ u16 vbuf[64 * 64];
    __shared__ u16 pls[4][1024];
    __shared__ float red[4];

    const int tid = threadIdx.x;
    const int w = tid >> 6, lane = tid & 63;
    const int lr = lane & 15, lg = lane >> 4;
    const int rl = lane >> 3, cch = lane & 7;
    const int bh = blockIdx.y, b = bh >> 4, h = bh & 15;
    const int i0 = blockIdx.x * 64;
    const int iw = i0 + 16 * w;

    const int lrh = lr >> 3, lrm = lr & 7;
    int pwidx[4], pridx[2];
    #pragma unroll
    for (int nb = 0; nb < 4; ++nb)
        pwidx[nb] = (((nb * 2 + lrh) ^ (lg * 2)) * 8) + lrm;
    #pragma unroll
    for (int ks = 0; ks < 2; ++ks)
        pridx[ks] = lr * 64 + (((ks * 4 + lg) ^ ((lr >> 2) * 2)) * 8);

    const u16* kbase = ckcv + ((size_t)(b * 256)) * 2048 + h * 64;
    const u16* vbase = cvt + ((size_t)(bh * 64)) * 256;

    bf16x8 qf[2];
    #pragma unroll
    for (int ks = 0; ks < 2; ++ks)
        qf[ks] = *(const bf16x8*)(qb + ((size_t)(b * 1024 + iw + lr)) * 1024
                                  + h * 64 + ks * 32 + lg * 8);

    const f32x4 z = {0.f, 0.f, 0.f, 0.f};
    f32x4 od[4];
    float mloc[4], lloc[4];
    #pragma unroll
    for (int nb = 0; nb < 4; ++nb) od[nb] = z;
    #pragma unroll
    for (int jr = 0; jr < 4; ++jr) { mloc[jr] = -1e30f; lloc[jr] = 0.f; }

    for (int t = 0; t < 4; ++t) {
        const int j0 = t * 64;
        __syncthreads();
        #pragma unroll
        for (int q = 0; q < 2; ++q) {
            int row = 16 * w + 8 * q + rl;
            gload_lds16(kbase + (size_t)(j0 + row) * 2048 + ((cch ^ rl) * 8),
                        &kbuf[(16 * w + 8 * q) * 64]);
            gload_lds16(vbase + (size_t)row * 256 + j0 + ((cch ^ rl) * 8),
                        &vbuf[(16 * w + 8 * q) * 64]);
        }
        __syncthreads();

        f32x4 qk[4];
        #pragma unroll
        for (int nb = 0; nb < 4; ++nb) qk[nb] = z;
        #pragma unroll
        for (int ks = 0; ks < 2; ++ks)
            #pragma unroll
            for (int nb = 0; nb < 4; ++nb) {
                int row = nb * 16 + lr;
                bf16x8 kb = *(const bf16x8*)&kbuf[row * 64 + (((4 * ks + lg) ^ (row & 7)) * 8)];
                qk[nb] = __builtin_amdgcn_mfma_f32_16x16x32_bf16(qf[ks], kb, qk[nb], 0, 0, 0);
            }

        #pragma unroll
        for (int jr = 0; jr < 4; ++jr) {
            const int r = lg * 4 + jr;
            float s0 = qk[0][jr] * C2, s1 = qk[1][jr] * C2;
            float s2 = qk[2][jr] * C2, s3 = qk[3][jr] * C2;
            float lm = fmaxf(fmaxf(s0, s1), fmaxf(s2, s3));
            if (__any(lm > mloc[jr] + 11.f)) {
                float tm = lm;
                #pragma unroll
                for (int mk = 1; mk < 16; mk <<= 1) tm = fmaxf(tm, __shfl_xor(tm, mk));
                float mn = fmaxf(mloc[jr], tm);
                float corr = exp2a(mloc[jr] - mn);
                mloc[jr] = mn; lloc[jr] *= corr;
                od[0][jr] *= corr; od[1][jr] *= corr; od[2][jr] *= corr; od[3][jr] *= corr;
            }
            float p0 = exp2a(s0 - mloc[jr]), p1 = exp2a(s1 - mloc[jr]);
            float p2 = exp2a(s2 - mloc[jr]), p3 = exp2a(s3 - mloc[jr]);
            unsigned pkA = cvtpk(p0, p1), pkB = cvtpk(p2, p3);
            u16* pw = &pls[w][r * 64];
            pw[pwidx[0]] = (u16)pkA; pw[pwidx[1]] = (u16)(pkA >> 16);
            pw[pwidx[2]] = (u16)pkB; pw[pwidx[3]] = (u16)(pkB >> 16);
            lloc[jr] += (p0 + p1) + (p2 + p3);
        }

        #pragma unroll
        for (int ks = 0; ks < 2; ++ks) {
            bf16x8 pa = *(const bf16x8*)&pls[w][pridx[ks]];
            #pragma unroll
            for (int nb = 0; nb < 4; ++nb) {
                int d = nb * 16 + lr;
                bf16x8 vb = *(const bf16x8*)&vbuf[d * 64 + (((4 * ks + lg) ^ (d & 7)) * 8)];
                od[nb] = __builtin_amdgcn_mfma_f32_16x16x32_bf16(pa, vb, od[nb], 0, 0, 0);
            }
        }
    }

    float local = 0.f;
    #pragma unroll
    for (int jr = 0; jr < 4; ++jr) {
        float l = lloc[jr];
        #pragma unroll
        for (int mk = 1; mk < 16; mk <<= 1) l += __shfl_xor(l, mk);
        float inv = 1.f / l;
        int ig = i0 + 16 * w + lg * 4 + jr;
        #pragma unroll
        for (int nb = 0; nb < 4; ++nb) {
            float o2 = od[nb][jr] * inv;
            float o1 = auxo[((size_t)(bh * 1024 + ig)) * 64 + nb * 16 + lr];
            float d = o1 - o2;
            local += d * d;
        }
    }
    #pragma unroll
    for (int mk = 1; mk < 64; mk <<= 1) local += __shfl_xor(local, mk);
    if (lane == 0) red[w] = local;
    __syncthreads();
    if (tid == 0) atomicAdd(acc, red[0] + red[1] + red[2] + red[3]);
}

__global__ void finish_aux(const float* __restrict__ acc, float* __restrict__ out)
{
    out[0] = acc[0] * (1.0f / 4194304.0f);
}

// ---------------- launch ----------------
extern "C" void kernel_launch(void* const* d_in, const int* in_sizes, int n_in,
                              void* d_out, int out_size, void* d_ws, size_t ws_size,
                              hipStream_t stream)
{
    const float* x     = (const float*)d_in[0];
    const float* mem   = (const float*)d_in[1];
    const float* cmem  = (const float*)d_in[2];
    const float* pos   = (const float*)d_in[3];
    const float* Wq    = (const float*)d_in[5];
    const float* Wkv   = (const float*)d_in[6];
    const float* Wout  = (const float*)d_in[7];
    const float* bout  = (const float*)d_in[8];
    const float* convw = (const float*)d_in[9];
    const float* convb = (const float*)d_in[10];

    float* out      = (float*)d_out;
    float* logits   = out;
    float* new_mem  = out + 4194304;
    float* new_cmem = out + 8388608;
    float* aux_out  = out + 9437184;

    char* p = (char*)d_ws;
    u16* kvb   = (u16*)p; p += (size_t)9216 * 2048 * 2;
    u16* qb    = (u16*)p; p += (size_t)4096 * 1024 * 2;
    u16* kvin  = (u16*)p; p += (size_t)9216 * 1024 * 2;   // reused as vt after kv GEMM
    u16* wkvt  = (u16*)p; p += (size_t)2048 * 1024 * 2;
    u16* wqt   = (u16*)p; p += (size_t)1024 * 1024 * 2;
    u16* woutt = (u16*)p; p += (size_t)1024 * 1024 * 2;
    u16* w2t   = (u16*)p; p += (size_t)1024 * 4096 * 2;   // reused as cvt after compress GEMM
    u16* peb   = (u16*)p; p += (size_t)16 * 2304 * 64 * 2;
    u16* xb    = (u16*)p; p += (size_t)4096 * 1024 * 2;   // reused (with memb) as auxo
    u16* memb  = (u16*)p; p += (size_t)4096 * 1024 * 2;
    u16* cmpb  = (u16*)p; p += (size_t)1024 * 1024 * 2;
    u16* ckcvb = (u16*)p; p += (size_t)1024 * 2048 * 2;
    u16* aob   = (u16*)p; p += (size_t)4096 * 1024 * 2;
    float* acc = (float*)p;
    u16* vt   = kvin;          // 4096 x 2304 u16, exact fit
    u16* cvt  = w2t;           // 4096 x 256 u16, fits
    float* auxo = (float*)xb;  // 4,194,304 f32 == xb+memb region exactly

    hipMemcpyAsync(new_mem, x, (size_t)4194304 * sizeof(float),
                   hipMemcpyDeviceToDevice, stream);

    cvt_bf16<<<4096, 256, 0, stream>>>(x, xb, 1048576);
    cvt_bf16<<<4096, 256, 0, stream>>>(mem, memb, 1048576);
    cvt_bf16<<<2304, 256, 0, stream>>>(pos, peb, 589824);
    concat_bf16<<<9216, 256, 0, stream>>>(x, mem, cmem, kvin);
    transpose_bf16<<<dim3(64, 32), 256, 0, stream>>>(Wkv, wkvt, 1024, 2048);
    transpose_bf16<<<dim3(32, 32), 256, 0, stream>>>(Wq, wqt, 1024, 1024);
    transpose_bf16<<<dim3(32, 32), 256, 0, stream>>>(Wout, woutt, 1024, 1024);
    w2t_bf16<<<16384, 256, 0, stream>>>(convw, w2t);

    gemm_bf16<<<dim3(16, 72), 256, 0, stream>>>(kvin, wkvt, nullptr, nullptr, kvb, 9216, 2048, 1024);
    transpose_v<<<dim3(36, 64), 256, 0, stream>>>(kvb, 2304, vt);
    gemm_bf16<<<dim3(8, 32), 256, 0, stream>>>(xb, wqt, nullptr, nullptr, qb, 4096, 1024, 1024);
    gemm_bf16<<<dim3(8, 8), 256, 0, stream>>>(memb, w2t, convb, new_cmem, cmpb, 1024, 1024, 4096);
    gemm_bf16<<<dim3(16, 8), 256, 0, stream>>>(cmpb, wkvt, nullptr, nullptr, ckcvb, 1024, 2048, 1024);
    transpose_v<<<dim3(4, 64), 256, 0, stream>>>(ckcvb, 256, cvt);

    // xb/memb dead from here -> auxo overlays them
    attn_main_fused<<<dim3(16, 64), 256, 0, stream>>>(qb, kvb, vt, peb, aob, auxo);
    gemm_bf16<<<dim3(8, 32), 256, 0, stream>>>(aob, woutt, bout, logits, nullptr, 4096, 1024, 1024);

    hipMemsetAsync(acc, 0, sizeof(float), stream);
    attn_aux_diff<<<dim3(16, 64), 256, 0, stream>>>(qb, ckcvb, cvt, auxo, acc);
    finish_aux<<<1, 1, 0, stream>>>(acc, aux_out);
}

// Round 7
// 507.682 us; speedup vs baseline: 1.6719x; 1.0512x over previous
//
#include <hip/hip_runtime.h>
#include <hip/hip_bf16.h>
#include <cstddef>

typedef unsigned short u16;
typedef __attribute__((ext_vector_type(8))) short bf16x8;
typedef __attribute__((ext_vector_type(4))) float f32x4;

#define C2 0.18033688011112042f   // 0.125 * log2(e)

__device__ __forceinline__ u16 f2b(float f) {
    unsigned u = __builtin_bit_cast(unsigned, f);
    unsigned r = (u + 0x7FFF + ((u >> 16) & 1)) >> 16;
    return (u16)r;
}

__device__ __forceinline__ float exp2a(float x) {
    float r; asm("v_exp_f32 %0, %1" : "=v"(r) : "v"(x)); return r;
}

__device__ __forceinline__ unsigned cvtpk(float lo, float hi) {
    unsigned r; asm("v_cvt_pk_bf16_f32 %0, %1, %2" : "=v"(r) : "v"(lo), "v"(hi));
    return r;
}

__device__ __forceinline__ void gload_lds16(const void* g, void* l) {
    __builtin_amdgcn_global_load_lds(
        (const __attribute__((address_space(1))) unsigned int*)g,
        (__attribute__((address_space(3))) unsigned int*)l, 16, 0, 0);
}

#define VDRAIN() asm volatile("s_waitcnt vmcnt(0)" ::: "memory")
#define SBAR() do { __builtin_amdgcn_sched_barrier(0); __builtin_amdgcn_s_barrier(); } while (0)

// ---------------- elementwise fp32 -> bf16 ----------------
__global__ __launch_bounds__(256) void cvt_bf16(const float* __restrict__ in,
                                                u16* __restrict__ out, int n4)
{
    int i = blockIdx.x * 256 + threadIdx.x;
    if (i >= n4) return;
    float4 v = ((const float4*)in)[i];
    union { u16 s[4]; uint2 u; } pk;
    pk.s[0] = f2b(v.x); pk.s[1] = f2b(v.y); pk.s[2] = f2b(v.z); pk.s[3] = f2b(v.w);
    ((uint2*)out)[i] = pk.u;
}

// ---------------- kv_input concat (bf16) ----------------
__global__ __launch_bounds__(256) void concat_bf16(
    const float* __restrict__ x, const float* __restrict__ mem,
    const float* __restrict__ cmem, u16* __restrict__ out)
{
    int rowg = blockIdx.x;               // 0..9215
    int b = rowg / 2304, rr = rowg % 2304;
    const float* src = (rr < 256)  ? cmem + ((size_t)b * 256 + rr) * 1024
                     : (rr < 1280) ? mem  + ((size_t)b * 1024 + (rr - 256)) * 1024
                                   : x    + ((size_t)b * 1024 + (rr - 1280)) * 1024;
    float4 v = ((const float4*)src)[threadIdx.x];
    union { u16 s[4]; uint2 u; } pk;
    pk.s[0] = f2b(v.x); pk.s[1] = f2b(v.y); pk.s[2] = f2b(v.z); pk.s[3] = f2b(v.w);
    ((uint2*)(out + (size_t)rowg * 1024))[threadIdx.x] = pk.u;
}

// ---------------- transpose fp32 [K][N] -> bf16 [N][K] ----------------
__global__ __launch_bounds__(256) void transpose_bf16(
    const float* __restrict__ in, u16* __restrict__ out, int K, int N)
{
    __shared__ float t[32][33];
    int k0 = blockIdx.y * 32, n0 = blockIdx.x * 32;
    int tx = threadIdx.x & 31, ty = threadIdx.x >> 5;
    #pragma unroll
    for (int p = 0; p < 4; ++p)
        t[ty + 8 * p][tx] = in[(size_t)(k0 + ty + 8 * p) * N + n0 + tx];
    __syncthreads();
    #pragma unroll
    for (int p = 0; p < 4; ++p)
        out[(size_t)(n0 + ty + 8 * p) * K + k0 + tx] = f2b(t[tx][ty + 8 * p]);
}

// ---------------- conv_w[o,i,r] -> W2t[o][r*1024+i] bf16 ----------------
__global__ __launch_bounds__(256) void w2t_bf16(const float* __restrict__ cw,
                                                u16* __restrict__ out)
{
    size_t idx = (size_t)blockIdx.x * 256 + threadIdx.x;  // 1024*4096
    int o = (int)(idx >> 12), k = (int)(idx & 4095);
    out[idx] = f2b(cw[(size_t)o * 4096 + (k & 1023) * 4 + (k >> 10)]);
}

// ---------------- V half of [rows][2048] -> Vt[(bh*64+d)][rows] ----------------
__global__ __launch_bounds__(256) void transpose_v(
    const u16* __restrict__ src, int R, u16* __restrict__ dst)
{
    __shared__ u16 t[64 * 65];
    int bh = blockIdx.y, b = bh >> 4, h = bh & 15;
    int j0 = blockIdx.x * 64;
    int tid = threadIdx.x;
    #pragma unroll
    for (int p = 0; p < 2; ++p) {
        int idx = tid + p * 256;
        int j = idx >> 3, c = idx & 7;
        uint4 v = *(const uint4*)(src + ((size_t)(b * R + j0 + j)) * 2048 + 1024 + h * 64 + c * 8);
        const u16* vv = (const u16*)&v;
        #pragma unroll
        for (int u2 = 0; u2 < 8; ++u2) t[j * 65 + c * 8 + u2] = vv[u2];
    }
    __syncthreads();
    #pragma unroll
    for (int p = 0; p < 2; ++p) {
        int idx = tid + p * 256;
        int jc = idx & 7, d = idx >> 3;
        union { u16 s[8]; uint4 u; } pk;
        #pragma unroll
        for (int u2 = 0; u2 < 8; ++u2) pk.s[u2] = t[(jc * 8 + u2) * 65 + d];
        *(uint4*)(dst + ((size_t)(bh * 64 + d)) * (size_t)R + j0 + jc * 8) = pk.u;
    }
}

// ---------------- bf16 MFMA GEMM: C[M,N] = (A[M,K] @ Bt[N,K]^T + bias) ----------------
// Cb gets f2b(v * cscale); Cf gets v (unscaled).
__global__ __launch_bounds__(256) void gemm_bf16(
    const u16* __restrict__ A, const u16* __restrict__ Bt,
    const float* __restrict__ bias, float* __restrict__ Cf,
    u16* __restrict__ Cb, int M, int N, int K, float cscale)
{
    __shared__ u16 Al[128 * 32];
    __shared__ u16 Bl[128 * 32];
    const int tid = threadIdx.x, w = tid >> 6, lane = tid & 63;
    const int lr = lane & 15, lg = lane >> 4;
    const int bm0 = blockIdx.y * 128, bn0 = blockIdx.x * 128;
    const int wr = (w >> 1) * 64, wc = (w & 1) * 64;

    f32x4 acc[4][4];
    const f32x4 z = {0.f, 0.f, 0.f, 0.f};
    #pragma unroll
    for (int mb = 0; mb < 4; ++mb)
        #pragma unroll
        for (int nb = 0; nb < 4; ++nb) acc[mb][nb] = z;

    for (int k0 = 0; k0 < K; k0 += 32) {
        __syncthreads();
        #pragma unroll
        for (int q = 0; q < 2; ++q) {
            int chunk = w * 2 + q;
            int row = chunk * 16 + (lane >> 2);
            int sg = (lane & 3) * 8;
            gload_lds16(A + (size_t)(bm0 + row) * K + k0 + sg, &Al[chunk * 512]);
            gload_lds16(Bt + (size_t)(bn0 + row) * K + k0 + sg, &Bl[chunk * 512]);
        }
        __syncthreads();
        bf16x8 af[4], bf[4];
        #pragma unroll
        for (int mb = 0; mb < 4; ++mb)
            af[mb] = *(const bf16x8*)&Al[(wr + mb * 16 + lr) * 32 + lg * 8];
        #pragma unroll
        for (int nb = 0; nb < 4; ++nb)
            bf[nb] = *(const bf16x8*)&Bl[(wc + nb * 16 + lr) * 32 + lg * 8];
        #pragma unroll
        for (int mb = 0; mb < 4; ++mb)
            #pragma unroll
            for (int nb = 0; nb < 4; ++nb)
                acc[mb][nb] = __builtin_amdgcn_mfma_f32_16x16x32_bf16(
                    af[mb], bf[nb], acc[mb][nb], 0, 0, 0);
    }

    #pragma unroll
    for (int mb = 0; mb < 4; ++mb)
        #pragma unroll
        for (int nb = 0; nb < 4; ++nb)
            #pragma unroll
            for (int jr = 0; jr < 4; ++jr) {
                int row = bm0 + wr + mb * 16 + lg * 4 + jr;
                int col = bn0 + wc + nb * 16 + lr;
                float v = acc[mb][nb][jr] + (bias ? bias[col] : 0.f);
                if (Cf) Cf[(size_t)row * N + col] = v;
                if (Cb) Cb[(size_t)row * N + col] = f2b(v * cscale);
            }
}

// ---------------- fused main attention + aux phase-0 (no max tracking) ----------------
// q is pre-scaled by C2, so P = exp2(qk + qp) directly; |s| <= ~10 by norm bounds.
__global__ __launch_bounds__(256) void attn_main_fused(
    const u16* __restrict__ qb,    // (4,1024,1024) bf16, pre-scaled by C2
    const u16* __restrict__ kvb,   // (4,2304,2048) bf16 k|v
    const u16* __restrict__ vt,    // (64bh*64d, 2304) bf16  V^T
    const u16* __restrict__ peb,   // (16,2304,64) bf16
    u16* __restrict__ outb,        // (4,1024,1024) bf16
    float* __restrict__ auxo)      // (64bh,1024,64) fp32 aux phase-0 out
{
    __shared__ u16 kbuf[64 * 64];      // 8 KB
    __shared__ u16 vbuf[64 * 64];      // 8 KB  [d][j-chunks] swizzled
    __shared__ u16 pering[128 * 64];   // 16 KB ring
    __shared__ u16 pls[4][1024];       // 8 KB, XOR-swizzled P

    const int tid = threadIdx.x;
    const int w = tid >> 6, lane = tid & 63;
    const int lr = lane & 15, lg = lane >> 4;
    const int rl = lane >> 3, cch = lane & 7;
    const int bh = blockIdx.y, b = bh >> 4, h = bh & 15;
    const int i0 = blockIdx.x * 64;
    const int iw = i0 + 16 * w;
    const int jb0 = 960 - i0;

    // per-thread constant pls indices
    const int lrh = lr >> 3, lrm = lr & 7;
    int pwidx[4], pridx[2];
    #pragma unroll
    for (int nb = 0; nb < 4; ++nb)
        pwidx[nb] = (((nb * 2 + lrh) ^ (lg * 2)) * 8) + lrm;
    #pragma unroll
    for (int ks = 0; ks < 2; ++ks)
        pridx[ks] = lr * 64 + (((ks * 4 + lg) ^ ((lr >> 2) * 2)) * 8);

    bf16x8 qf[2];
    #pragma unroll
    for (int ks = 0; ks < 2; ++ks)
        qf[ks] = *(const bf16x8*)(qb + ((size_t)(b * 1024 + iw + lr)) * 1024
                                  + h * 64 + ks * 32 + lg * 8);

    const f32x4 z = {0.f, 0.f, 0.f, 0.f};
    f32x4 od[4], od2[4];
    float lloc[4], ll2[4];
    #pragma unroll
    for (int nb = 0; nb < 4; ++nb) { od[nb] = z; od2[nb] = z; }
    #pragma unroll
    for (int jr = 0; jr < 4; ++jr) { lloc[jr] = 0.f; ll2[jr] = 0.f; }

    // ---- prologue: K(0), V(0), full 128-row PE band ----
    #pragma unroll
    for (int q = 0; q < 2; ++q) {
        int row = 16 * w + 8 * q + rl;
        gload_lds16(kvb + ((size_t)(b * 2304 + row)) * 2048 + h * 64 + ((cch ^ rl) * 8),
                    &kbuf[(16 * w + 8 * q) * 64]);
        gload_lds16(vt + ((size_t)(bh * 64 + row)) * 2304 + ((cch ^ rl) * 8),
                    &vbuf[(16 * w + 8 * q) * 64]);
    }
    #pragma unroll
    for (int q = 0; q < 4; ++q) {
        int rr = 32 * w + 8 * q;
        int a = jb0 + rr + rl;
        int srow = a > 2303 ? 2303 : a;
        gload_lds16(peb + ((size_t)(h * 2304 + srow)) * 64 + ((cch ^ rl) * 8),
                    &pering[((jb0 + rr) & 127) * 64]);
    }
    VDRAIN();
    __syncthreads();

    const int nt = ((i0 + 1343) >> 6) + 1;
    for (int t = 0; t < nt; ++t) {
        const int j0 = t * 64;
        const int jb = jb0 + j0;
        const bool more = (t + 1 < nt);

        // ---- QK & QP MFMA (read kbuf, pering) ----
        f32x4 qk[4], qp[5];
        #pragma unroll
        for (int nb = 0; nb < 4; ++nb) qk[nb] = z;
        #pragma unroll
        for (int f = 0; f < 5; ++f) qp[f] = z;
        __builtin_amdgcn_s_setprio(1);
        #pragma unroll
        for (int ks = 0; ks < 2; ++ks) {
            #pragma unroll
            for (int nb = 0; nb < 4; ++nb) {
                int row = nb * 16 + lr;
                bf16x8 kb = *(const bf16x8*)&kbuf[row * 64 + (((4 * ks + lg) ^ (row & 7)) * 8)];
                qk[nb] = __builtin_amdgcn_mfma_f32_16x16x32_bf16(qf[ks], kb, qk[nb], 0, 0, 0);
            }
            #pragma unroll
            for (int f = 0; f < 5; ++f) {
                int rel = 48 - 16 * w + f * 16 + lr;
                int slot = (jb + rel) & 127;
                bf16x8 pb = *(const bf16x8*)&pering[slot * 64 + (((4 * ks + lg) ^ (slot & 7)) * 8)];
                qp[f] = __builtin_amdgcn_mfma_f32_16x16x32_bf16(qf[ks], pb, qp[f], 0, 0, 0);
            }
        }
        __builtin_amdgcn_s_setprio(0);

        VDRAIN();   // retire own V(t) loads (issued after barrier C of t-1)
        SBAR();     // B: publishes V(t); certifies kbuf/pering reads of tile t

        if (more) { // stage K(t+1) and PE(t+1)
            const int j0n = j0 + 64;
            #pragma unroll
            for (int q = 0; q < 2; ++q) {
                int row = 16 * w + 8 * q + rl;
                gload_lds16(kvb + ((size_t)(b * 2304 + j0n + row)) * 2048 + h * 64 + ((cch ^ rl) * 8),
                            &kbuf[(16 * w + 8 * q) * 64]);
            }
            const int A0 = jb + 128;
            #pragma unroll
            for (int q = 0; q < 2; ++q) {
                int rr = A0 + 16 * w + 8 * q;
                int a = rr + rl;
                int srow = a > 2303 ? 2303 : a;
                gload_lds16(peb + ((size_t)(h * 2304 + srow)) * 64 + ((cch ^ rl) * 8),
                            &pering[(rr & 127) * 64]);
            }
        }

        // ---- main: mask + softmax (m == 0), shuffle qp gather ----
        const bool nomask = (j0 + 63 <= iw + 1280);
        #pragma unroll
        for (int jr = 0; jr < 4; ++jr) {
            const int r = lg * 4 + jr;
            const int ia = iw + r;
            const int src = (lane & 48) | ((lr + 15 - r) & 15);
            float rot0 = __shfl(qp[0][jr], src);
            float rot1 = __shfl(qp[1][jr], src);
            float rot2 = __shfl(qp[2][jr], src);
            float rot3 = __shfl(qp[3][jr], src);
            float rot4 = __shfl(qp[4][jr], src);
            const bool hi = (lr > r);
            float s0 = qk[0][jr] + (hi ? rot1 : rot0);
            float s1 = qk[1][jr] + (hi ? rot2 : rot1);
            float s2 = qk[2][jr] + (hi ? rot3 : rot2);
            float s3 = qk[3][jr] + (hi ? rot4 : rot3);
            if (!nomask) {
                s0 = (j0 + lr      <= ia + 1280) ? s0 : -1e30f;
                s1 = (j0 + lr + 16 <= ia + 1280) ? s1 : -1e30f;
                s2 = (j0 + lr + 32 <= ia + 1280) ? s2 : -1e30f;
                s3 = (j0 + lr + 48 <= ia + 1280) ? s3 : -1e30f;
            }
            float p0 = exp2a(s0), p1 = exp2a(s1);
            float p2 = exp2a(s2), p3 = exp2a(s3);
            unsigned pkA = cvtpk(p0, p1), pkB = cvtpk(p2, p3);
            u16* pw = &pls[w][r * 64];
            pw[pwidx[0]] = (u16)pkA; pw[pwidx[1]] = (u16)(pkA >> 16);
            pw[pwidx[2]] = (u16)pkB; pw[pwidx[3]] = (u16)(pkB >> 16);
            lloc[jr] += (p0 + p1) + (p2 + p3);
        }

        // ---- main PV MFMA ----
        __builtin_amdgcn_s_setprio(1);
        #pragma unroll
        for (int ks = 0; ks < 2; ++ks) {
            bf16x8 pa = *(const bf16x8*)&pls[w][pridx[ks]];
            #pragma unroll
            for (int nb = 0; nb < 4; ++nb) {
                int d = nb * 16 + lr;
                bf16x8 vb = *(const bf16x8*)&vbuf[d * 64 + (((4 * ks + lg) ^ (d & 7)) * 8)];
                od[nb] = __builtin_amdgcn_mfma_f32_16x16x32_bf16(pa, vb, od[nb], 0, 0, 0);
            }
        }
        __builtin_amdgcn_s_setprio(0);

        // ---- aux phase-0: kv rows 256..1279 == tiles 4..19 ----
        if (t >= 4 && t <= 19) {
            #pragma unroll
            for (int jr = 0; jr < 4; ++jr) {
                const int r = lg * 4 + jr;
                float p0 = exp2a(qk[0][jr]), p1 = exp2a(qk[1][jr]);
                float p2 = exp2a(qk[2][jr]), p3 = exp2a(qk[3][jr]);
                unsigned pkA = cvtpk(p0, p1), pkB = cvtpk(p2, p3);
                u16* pw = &pls[w][r * 64];
                pw[pwidx[0]] = (u16)pkA; pw[pwidx[1]] = (u16)(pkA >> 16);
                pw[pwidx[2]] = (u16)pkB; pw[pwidx[3]] = (u16)(pkB >> 16);
                ll2[jr] += (p0 + p1) + (p2 + p3);
            }
            __builtin_amdgcn_s_setprio(1);
            #pragma unroll
            for (int ks = 0; ks < 2; ++ks) {
                bf16x8 pa = *(const bf16x8*)&pls[w][pridx[ks]];
                #pragma unroll
                for (int nb = 0; nb < 4; ++nb) {
                    int d = nb * 16 + lr;
                    bf16x8 vb = *(const bf16x8*)&vbuf[d * 64 + (((4 * ks + lg) ^ (d & 7)) * 8)];
                    od2[nb] = __builtin_amdgcn_mfma_f32_16x16x32_bf16(pa, vb, od2[nb], 0, 0, 0);
                }
            }
            __builtin_amdgcn_s_setprio(0);
        }

        VDRAIN();   // retire own K(t+1)/PE(t+1) loads
        SBAR();     // C: publishes kbuf=K(t+1), pering; certifies vbuf/pls reads

        if (more) { // stage V(t+1)
            const int j0n = j0 + 64;
            #pragma unroll
            for (int q = 0; q < 2; ++q) {
                int row = 16 * w + 8 * q + rl;
                gload_lds16(vt + ((size_t)(bh * 64 + row)) * 2304 + j0n + ((cch ^ rl) * 8),
                            &vbuf[(16 * w + 8 * q) * 64]);
            }
        }
    }

    // ---- main epilogue ----
    #pragma unroll
    for (int jr = 0; jr < 4; ++jr) {
        float l = lloc[jr];
        #pragma unroll
        for (int mk = 1; mk < 16; mk <<= 1) l += __shfl_xor(l, mk);
        float inv = 1.f / l;
        int ia = iw + lg * 4 + jr;
        #pragma unroll
        for (int nb = 0; nb < 4; ++nb)
            outb[((size_t)(b * 1024 + ia)) * 1024 + h * 64 + nb * 16 + lr] =
                f2b(od[nb][jr] * inv);
    }
    // ---- aux phase-0 epilogue ----
    #pragma unroll
    for (int jr = 0; jr < 4; ++jr) {
        float l = ll2[jr];
        #pragma unroll
        for (int mk = 1; mk < 16; mk <<= 1) l += __shfl_xor(l, mk);
        float inv = 1.f / l;
        int ig = i0 + 16 * w + lg * 4 + jr;
        #pragma unroll
        for (int nb = 0; nb < 4; ++nb)
            auxo[((size_t)(bh * 1024 + ig)) * 64 + nb * 16 + lr] = od2[nb][jr] * inv;
    }
}

// ---------------- aux phase-1 (compressed KV) + squared diff ----------------
__global__ __launch_bounds__(256) void attn_aux_diff(
    const u16* __restrict__ qb, const u16* __restrict__ ckcv,
    const u16* __restrict__ cvt, const float* __restrict__ auxo,
    float* __restrict__ acc)
{
    __shared__ u16 kbuf[64 * 64];
    __shared__ u16 vbuf[64 * 64];
    __shared__ u16 pls[4][1024];
    __shared__ float red[4];

    const int tid = threadIdx.x;
    const int w = tid >> 6, lane = tid & 63;
    const int lr = lane & 15, lg = lane >> 4;
    const int rl = lane >> 3, cch = lane & 7;
    const int bh = blockIdx.y, b = bh >> 4, h = bh & 15;
    const int i0 = blockIdx.x * 64;
    const int iw = i0 + 16 * w;

    const int lrh = lr >> 3, lrm = lr & 7;
    int pwidx[4], pridx[2];
    #pragma unroll
    for (int nb = 0; nb < 4; ++nb)
        pwidx[nb] = (((nb * 2 + lrh) ^ (lg * 2)) * 8) + lrm;
    #pragma unroll
    for (int ks = 0; ks < 2; ++ks)
        pridx[ks] = lr * 64 + (((ks * 4 + lg) ^ ((lr >> 2) * 2)) * 8);

    const u16* kbase = ckcv + ((size_t)(b * 256)) * 2048 + h * 64;
    const u16* vbase = cvt + ((size_t)(bh * 64)) * 256;

    bf16x8 qf[2];
    #pragma unroll
    for (int ks = 0; ks < 2; ++ks)
        qf[ks] = *(const bf16x8*)(qb + ((size_t)(b * 1024 + iw + lr)) * 1024
                                  + h * 64 + ks * 32 + lg * 8);

    const f32x4 z = {0.f, 0.f, 0.f, 0.f};
    f32x4 od[4];
    float lloc[4];
    #pragma unroll
    for (int nb = 0; nb < 4; ++nb) od[nb] = z;
    #pragma unroll
    for (int jr = 0; jr < 4; ++jr) lloc[jr] = 0.f;

    for (int t = 0; t < 4; ++t) {
        const int j0 = t * 64;
        __syncthreads();
        #pragma unroll
        for (int q = 0; q < 2; ++q) {
            int row = 16 * w + 8 * q + rl;
            gload_lds16(kbase + (size_t)(j0 + row) * 2048 + ((cch ^ rl) * 8),
                        &kbuf[(16 * w + 8 * q) * 64]);
            gload_lds16(vbase + (size_t)row * 256 + j0 + ((cch ^ rl) * 8),
                        &vbuf[(16 * w + 8 * q) * 64]);
        }
        __syncthreads();

        f32x4 qk[4];
        #pragma unroll
        for (int nb = 0; nb < 4; ++nb) qk[nb] = z;
        #pragma unroll
        for (int ks = 0; ks < 2; ++ks)
            #pragma unroll
            for (int nb = 0; nb < 4; ++nb) {
                int row = nb * 16 + lr;
                bf16x8 kb = *(const bf16x8*)&kbuf[row * 64 + (((4 * ks + lg) ^ (row & 7)) * 8)];
                qk[nb] = __builtin_amdgcn_mfma_f32_16x16x32_bf16(qf[ks], kb, qk[nb], 0, 0, 0);
            }

        #pragma unroll
        for (int jr = 0; jr < 4; ++jr) {
            const int r = lg * 4 + jr;
            float p0 = exp2a(qk[0][jr]), p1 = exp2a(qk[1][jr]);
            float p2 = exp2a(qk[2][jr]), p3 = exp2a(qk[3][jr]);
            unsigned pkA = cvtpk(p0, p1), pkB = cvtpk(p2, p3);
            u16* pw = &pls[w][r * 64];
            pw[pwidx[0]] = (u16)pkA; pw[pwidx[1]] = (u16)(pkA >> 16);
            pw[pwidx[2]] = (u16)pkB; pw[pwidx[3]] = (u16)(pkB >> 16);
            lloc[jr] += (p0 + p1) + (p2 + p3);
        }

        #pragma unroll
        for (int ks = 0; ks < 2; ++ks) {
            bf16x8 pa = *(const bf16x8*)&pls[w][pridx[ks]];
            #pragma unroll
            for (int nb = 0; nb < 4; ++nb) {
                int d = nb * 16 + lr;
                bf16x8 vb = *(const bf16x8*)&vbuf[d * 64 + (((4 * ks + lg) ^ (d & 7)) * 8)];
                od[nb] = __builtin_amdgcn_mfma_f32_16x16x32_bf16(pa, vb, od[nb], 0, 0, 0);
            }
        }
    }

    float local = 0.f;
    #pragma unroll
    for (int jr = 0; jr < 4; ++jr) {
        float l = lloc[jr];
        #pragma unroll
        for (int mk = 1; mk < 16; mk <<= 1) l += __shfl_xor(l, mk);
        float inv = 1.f / l;
        int ig = i0 + 16 * w + lg * 4 + jr;
        #pragma unroll
        for (int nb = 0; nb < 4; ++nb) {
            float o2 = od[nb][jr] * inv;
            float o1 = auxo[((size_t)(bh * 1024 + ig)) * 64 + nb * 16 + lr];
            float d = o1 - o2;
            local += d * d;
        }
    }
    #pragma unroll
    for (int mk = 1; mk < 64; mk <<= 1) local += __shfl_xor(local, mk);
    if (lane == 0) red[w] = local;
    __syncthreads();
    if (tid == 0) atomicAdd(acc, red[0] + red[1] + red[2] + red[3]);
}

__global__ void finish_aux(const float* __restrict__ acc, float* __restrict__ out)
{
    out[0] = acc[0] * (1.0f / 4194304.0f);
}

// ---------------- launch ----------------
extern "C" void kernel_launch(void* const* d_in, const int* in_sizes, int n_in,
                              void* d_out, int out_size, void* d_ws, size_t ws_size,
                              hipStream_t stream)
{
    const float* x     = (const float*)d_in[0];
    const float* mem   = (const float*)d_in[1];
    const float* cmem  = (const float*)d_in[2];
    const float* pos   = (const float*)d_in[3];
    const float* Wq    = (const float*)d_in[5];
    const float* Wkv   = (const float*)d_in[6];
    const float* Wout  = (const float*)d_in[7];
    const float* bout  = (const float*)d_in[8];
    const float* convw = (const float*)d_in[9];
    const float* convb = (const float*)d_in[10];

    float* out      = (float*)d_out;
    float* logits   = out;
    float* new_mem  = out + 4194304;
    float* new_cmem = out + 8388608;
    float* aux_out  = out + 9437184;

    char* p = (char*)d_ws;
    u16* kvb   = (u16*)p; p += (size_t)9216 * 2048 * 2;
    u16* qb    = (u16*)p; p += (size_t)4096 * 1024 * 2;
    u16* kvin  = (u16*)p; p += (size_t)9216 * 1024 * 2;   // reused as vt after kv GEMM
    u16* wkvt  = (u16*)p; p += (size_t)2048 * 1024 * 2;
    u16* wqt   = (u16*)p; p += (size_t)1024 * 1024 * 2;
    u16* woutt = (u16*)p; p += (size_t)1024 * 1024 * 2;
    u16* w2t   = (u16*)p; p += (size_t)1024 * 4096 * 2;   // reused as cvt after compress GEMM
    u16* peb   = (u16*)p; p += (size_t)16 * 2304 * 64 * 2;
    u16* xb    = (u16*)p; p += (size_t)4096 * 1024 * 2;   // reused (with memb) as auxo
    u16* memb  = (u16*)p; p += (size_t)4096 * 1024 * 2;
    u16* cmpb  = (u16*)p; p += (size_t)1024 * 1024 * 2;
    u16* ckcvb = (u16*)p; p += (size_t)1024 * 2048 * 2;
    u16* aob   = (u16*)p; p += (size_t)4096 * 1024 * 2;
    float* acc = (float*)p;
    u16* vt   = kvin;          // 4096 x 2304 u16, exact fit
    u16* cvt  = w2t;           // 4096 x 256 u16, fits
    float* auxo = (float*)xb;  // 4,194,304 f32 == xb+memb region exactly

    hipMemcpyAsync(new_mem, x, (size_t)4194304 * sizeof(float),
                   hipMemcpyDeviceToDevice, stream);

    cvt_bf16<<<4096, 256, 0, stream>>>(x, xb, 1048576);
    cvt_bf16<<<4096, 256, 0, stream>>>(mem, memb, 1048576);
    cvt_bf16<<<2304, 256, 0, stream>>>(pos, peb, 589824);
    concat_bf16<<<9216, 256, 0, stream>>>(x, mem, cmem, kvin);
    transpose_bf16<<<dim3(64, 32), 256, 0, stream>>>(Wkv, wkvt, 1024, 2048);
    transpose_bf16<<<dim3(32, 32), 256, 0, stream>>>(Wq, wqt, 1024, 1024);
    transpose_bf16<<<dim3(32, 32), 256, 0, stream>>>(Wout, woutt, 1024, 1024);
    w2t_bf16<<<16384, 256, 0, stream>>>(convw, w2t);

    gemm_bf16<<<dim3(16, 72), 256, 0, stream>>>(kvin, wkvt, nullptr, nullptr, kvb, 9216, 2048, 1024, 1.f);
    transpose_v<<<dim3(36, 64), 256, 0, stream>>>(kvb, 2304, vt);
    // q pre-scaled by C2 = 0.125*log2(e): attention kernels use exp2(s) directly
    gemm_bf16<<<dim3(8, 32), 256, 0, stream>>>(xb, wqt, nullptr, nullptr, qb, 4096, 1024, 1024, C2);
    gemm_bf16<<<dim3(8, 8), 256, 0, stream>>>(memb, w2t, convb, new_cmem, cmpb, 1024, 1024, 4096, 1.f);
    gemm_bf16<<<dim3(16, 8), 256, 0, stream>>>(cmpb, wkvt, nullptr, nullptr, ckcvb, 1024, 2048, 1024, 1.f);
    transpose_v<<<dim3(4, 64), 256, 0, stream>>>(ckcvb, 256, cvt);

    // xb/memb dead from here -> auxo overlays them
    attn_main_fused<<<dim3(16, 64), 256, 0, stream>>>(qb, kvb, vt, peb, aob, auxo);
    gemm_bf16<<<dim3(8, 32), 256, 0, stream>>>(aob, woutt, bout, logits, nullptr, 4096, 1024, 1024, 1.f);

    hipMemsetAsync(acc, 0, sizeof(float), stream);
    attn_aux_diff<<<dim3(16, 64), 256, 0, stream>>>(qb, ckcvb, cvt, auxo, acc);
    finish_aux<<<1, 1, 0, stream>>>(acc, aux_out);
}

// Round 10
// 486.819 us; speedup vs baseline: 1.7435x; 1.0429x over previous
//
#include <hip/hip_runtime.h>
#include <hip/hip_bf16.h>
#include <cstddef>

typedef unsigned short u16;
typedef __attribute__((ext_vector_type(8))) short bf16x8;
typedef __attribute__((ext_vector_type(4))) float f32x4;

#define C2 0.18033688011112042f   // 0.125 * log2(e)

__device__ __forceinline__ u16 f2b(float f) {
    unsigned u = __builtin_bit_cast(unsigned, f);
    unsigned r = (u + 0x7FFF + ((u >> 16) & 1)) >> 16;
    return (u16)r;
}

__device__ __forceinline__ float exp2a(float x) {
    float r; asm("v_exp_f32 %0, %1" : "=v"(r) : "v"(x)); return r;
}

__device__ __forceinline__ unsigned cvtpk(float lo, float hi) {
    unsigned r; asm("v_cvt_pk_bf16_f32 %0, %1, %2" : "=v"(r) : "v"(lo), "v"(hi));
    return r;
}

__device__ __forceinline__ void gload_lds16(const void* g, void* l) {
    __builtin_amdgcn_global_load_lds(
        (const __attribute__((address_space(1))) unsigned int*)g,
        (__attribute__((address_space(3))) unsigned int*)l, 16, 0, 0);
}

#define VDRAIN() asm volatile("s_waitcnt vmcnt(0)" ::: "memory")
#define SBAR() do { __builtin_amdgcn_sched_barrier(0); __builtin_amdgcn_s_barrier(); } while (0)

// ---------------- elementwise fp32 -> bf16 ----------------
__global__ __launch_bounds__(256) void cvt_bf16(const float* __restrict__ in,
                                                u16* __restrict__ out, int n4)
{
    int i = blockIdx.x * 256 + threadIdx.x;
    if (i >= n4) return;
    float4 v = ((const float4*)in)[i];
    union { u16 s[4]; uint2 u; } pk;
    pk.s[0] = f2b(v.x); pk.s[1] = f2b(v.y); pk.s[2] = f2b(v.z); pk.s[3] = f2b(v.w);
    ((uint2*)out)[i] = pk.u;
}

// ---------------- kv_input concat (bf16) ----------------
__global__ __launch_bounds__(256) void concat_bf16(
    const float* __restrict__ x, const float* __restrict__ mem,
    const float* __restrict__ cmem, u16* __restrict__ out)
{
    int rowg = blockIdx.x;               // 0..9215
    int b = rowg / 2304, rr = rowg % 2304;
    const float* src = (rr < 256)  ? cmem + ((size_t)b * 256 + rr) * 1024
                     : (rr < 1280) ? mem  + ((size_t)b * 1024 + (rr - 256)) * 1024
                                   : x    + ((size_t)b * 1024 + (rr - 1280)) * 1024;
    float4 v = ((const float4*)src)[threadIdx.x];
    union { u16 s[4]; uint2 u; } pk;
    pk.s[0] = f2b(v.x); pk.s[1] = f2b(v.y); pk.s[2] = f2b(v.z); pk.s[3] = f2b(v.w);
    ((uint2*)(out + (size_t)rowg * 1024))[threadIdx.x] = pk.u;
}

// ---------------- transpose fp32 [K][N] -> bf16 [N][K] ----------------
__global__ __launch_bounds__(256) void transpose_bf16(
    const float* __restrict__ in, u16* __restrict__ out, int K, int N)
{
    __shared__ float t[32][33];
    int k0 = blockIdx.y * 32, n0 = blockIdx.x * 32;
    int tx = threadIdx.x & 31, ty = threadIdx.x >> 5;
    #pragma unroll
    for (int p = 0; p < 4; ++p)
        t[ty + 8 * p][tx] = in[(size_t)(k0 + ty + 8 * p) * N + n0 + tx];
    __syncthreads();
    #pragma unroll
    for (int p = 0; p < 4; ++p)
        out[(size_t)(n0 + ty + 8 * p) * K + k0 + tx] = f2b(t[tx][ty + 8 * p]);
}

// ---------------- conv_w[o,i,r] -> W2t[o][r*1024+i] bf16 ----------------
__global__ __launch_bounds__(256) void w2t_bf16(const float* __restrict__ cw,
                                                u16* __restrict__ out)
{
    size_t idx = (size_t)blockIdx.x * 256 + threadIdx.x;  // 1024*4096
    int o = (int)(idx >> 12), k = (int)(idx & 4095);
    out[idx] = f2b(cw[(size_t)o * 4096 + (k & 1023) * 4 + (k >> 10)]);
}

// ---------------- V half of [rows][2048] -> Vt[(bh*64+d)][rows] ----------------
__global__ __launch_bounds__(256) void transpose_v(
    const u16* __restrict__ src, int R, u16* __restrict__ dst)
{
    __shared__ u16 t[64 * 65];
    int bh = blockIdx.y, b = bh >> 4, h = bh & 15;
    int j0 = blockIdx.x * 64;
    int tid = threadIdx.x;
    #pragma unroll
    for (int p = 0; p < 2; ++p) {
        int idx = tid + p * 256;
        int j = idx >> 3, c = idx & 7;
        uint4 v = *(const uint4*)(src + ((size_t)(b * R + j0 + j)) * 2048 + 1024 + h * 64 + c * 8);
        const u16* vv = (const u16*)&v;
        #pragma unroll
        for (int u2 = 0; u2 < 8; ++u2) t[j * 65 + c * 8 + u2] = vv[u2];
    }
    __syncthreads();
    #pragma unroll
    for (int p = 0; p < 2; ++p) {
        int idx = tid + p * 256;
        int jc = idx & 7, d = idx >> 3;
        union { u16 s[8]; uint4 u; } pk;
        #pragma unroll
        for (int u2 = 0; u2 < 8; ++u2) pk.s[u2] = t[(jc * 8 + u2) * 65 + d];
        *(uint4*)(dst + ((size_t)(bh * 64 + d)) * (size_t)R + j0 + jc * 8) = pk.u;
    }
}

// ---------------- bf16 MFMA GEMM: C[M,N] = (A' @ Bt^T + bias) ----------------
// A row remap: arow = row + (row>>ashift)*apad  (apad=0 -> plain).
// Q GEMM:       1024-row batches in 2304-row kv layout, K=1024: ashift=10, apad=1280
// compress GEMM: 256-row batches (K=4096) in 2304-row kv layout: ashift=8,  apad=320
// Cb gets f2b(v * cscale); Cf gets v (unscaled).
__global__ __launch_bounds__(256) void gemm_bf16(
    const u16* __restrict__ A, const u16* __restrict__ Bt,
    const float* __restrict__ bias, float* __restrict__ Cf,
    u16* __restrict__ Cb, int M, int N, int K, float cscale, int apad, int ashift)
{
    __shared__ u16 Al[128 * 32];
    __shared__ u16 Bl[128 * 32];
    const int tid = threadIdx.x, w = tid >> 6, lane = tid & 63;
    const int lr = lane & 15, lg = lane >> 4;
    const int bm0 = blockIdx.y * 128, bn0 = blockIdx.x * 128;
    const int wr = (w >> 1) * 64, wc = (w & 1) * 64;

    f32x4 acc[4][4];
    const f32x4 z = {0.f, 0.f, 0.f, 0.f};
    #pragma unroll
    for (int mb = 0; mb < 4; ++mb)
        #pragma unroll
        for (int nb = 0; nb < 4; ++nb) acc[mb][nb] = z;

    for (int k0 = 0; k0 < K; k0 += 32) {
        __syncthreads();
        #pragma unroll
        for (int q = 0; q < 2; ++q) {
            int chunk = w * 2 + q;
            int row = bm0 + chunk * 16 + (lane >> 2);
            int arow = row + ((row >> ashift) * apad);
            int sg = (lane & 3) * 8;
            gload_lds16(A + (size_t)arow * K + k0 + sg, &Al[chunk * 512]);
            gload_lds16(Bt + (size_t)(bn0 + chunk * 16 + (lane >> 2)) * K + k0 + sg, &Bl[chunk * 512]);
        }
        __syncthreads();
        bf16x8 af[4], bf[4];
        #pragma unroll
        for (int mb = 0; mb < 4; ++mb)
            af[mb] = *(const bf16x8*)&Al[(wr + mb * 16 + lr) * 32 + lg * 8];
        #pragma unroll
        for (int nb = 0; nb < 4; ++nb)
            bf[nb] = *(const bf16x8*)&Bl[(wc + nb * 16 + lr) * 32 + lg * 8];
        #pragma unroll
        for (int mb = 0; mb < 4; ++mb)
            #pragma unroll
            for (int nb = 0; nb < 4; ++nb)
                acc[mb][nb] = __builtin_amdgcn_mfma_f32_16x16x32_bf16(
                    af[mb], bf[nb], acc[mb][nb], 0, 0, 0);
    }

    #pragma unroll
    for (int mb = 0; mb < 4; ++mb)
        #pragma unroll
        for (int nb = 0; nb < 4; ++nb)
            #pragma unroll
            for (int jr = 0; jr < 4; ++jr) {
                int row = bm0 + wr + mb * 16 + lg * 4 + jr;
                int col = bn0 + wc + nb * 16 + lr;
                float v = acc[mb][nb][jr] + (bias ? bias[col] : 0.f);
                if (Cf) Cf[(size_t)row * N + col] = v;
                if (Cb) Cb[(size_t)row * N + col] = f2b(v * cscale);
            }
}

// ---------------- fused main attention + aux phase-0 (no max tracking) ----------------
// q pre-scaled by C2; 1-D grid 1024 with XCD-bijective decode so all 16 i-tiles
// of one (b,h) land on the same XCD -> K/V/PE L2 reuse.
__global__ __launch_bounds__(256) void attn_main_fused(
    const u16* __restrict__ qb,    // (4,1024,1024) bf16, pre-scaled by C2
    const u16* __restrict__ kvb,   // (4,2304,2048) bf16 k|v
    const u16* __restrict__ vt,    // (64bh*64d, 2304) bf16  V^T
    const u16* __restrict__ peb,   // (16,2304,64) bf16
    u16* __restrict__ outb,        // (4,1024,1024) bf16
    float* __restrict__ auxo)      // (64bh,1024,64) fp32 aux phase-0 out
{
    __shared__ u16 kbuf[64 * 64];      // 8 KB
    __shared__ u16 vbuf[64 * 64];      // 8 KB  [d][j-chunks] swizzled
    __shared__ u16 pering[128 * 64];   // 16 KB ring
    __shared__ u16 pls[4][1024];       // 8 KB, XOR-swizzled P

    const int tid = threadIdx.x;
    const int w = tid >> 6, lane = tid & 63;
    const int lr = lane & 15, lg = lane >> 4;
    const int rl = lane >> 3, cch = lane & 7;
    // XCD-bijective decode: xcd = id&7 (round-robin dispatch), 8 bh per XCD
    const int id = blockIdx.x;
    const int slot = id >> 3;
    const int bh = (id & 7) + ((slot >> 4) << 3);
    const int b = bh >> 4, h = bh & 15;
    const int i0 = (slot & 15) * 64;
    const int iw = i0 + 16 * w;
    const int jb0 = 960 - i0;

    // per-thread constant pls indices
    const int lrh = lr >> 3, lrm = lr & 7;
    int pwidx[4], pridx[2];
    #pragma unroll
    for (int nb = 0; nb < 4; ++nb)
        pwidx[nb] = (((nb * 2 + lrh) ^ (lg * 2)) * 8) + lrm;
    #pragma unroll
    for (int ks = 0; ks < 2; ++ks)
        pridx[ks] = lr * 64 + (((ks * 4 + lg) ^ ((lr >> 2) * 2)) * 8);

    bf16x8 qf[2];
    #pragma unroll
    for (int ks = 0; ks < 2; ++ks)
        qf[ks] = *(const bf16x8*)(qb + ((size_t)(b * 1024 + iw + lr)) * 1024
                                  + h * 64 + ks * 32 + lg * 8);

    const f32x4 z = {0.f, 0.f, 0.f, 0.f};
    f32x4 od[4], od2[4];
    float lloc[4], ll2[4];
    #pragma unroll
    for (int nb = 0; nb < 4; ++nb) { od[nb] = z; od2[nb] = z; }
    #pragma unroll
    for (int jr = 0; jr < 4; ++jr) { lloc[jr] = 0.f; ll2[jr] = 0.f; }

    // ---- prologue: K(0), V(0), full 128-row PE band ----
    #pragma unroll
    for (int q = 0; q < 2; ++q) {
        int row = 16 * w + 8 * q + rl;
        gload_lds16(kvb + ((size_t)(b * 2304 + row)) * 2048 + h * 64 + ((cch ^ rl) * 8),
                    &kbuf[(16 * w + 8 * q) * 64]);
        gload_lds16(vt + ((size_t)(bh * 64 + row)) * 2304 + ((cch ^ rl) * 8),
                    &vbuf[(16 * w + 8 * q) * 64]);
    }
    #pragma unroll
    for (int q = 0; q < 4; ++q) {
        int rr = 32 * w + 8 * q;
        int a = jb0 + rr + rl;
        int srow = a > 2303 ? 2303 : a;
        gload_lds16(peb + ((size_t)(h * 2304 + srow)) * 64 + ((cch ^ rl) * 8),
                    &pering[((jb0 + rr) & 127) * 64]);
    }
    VDRAIN();
    __syncthreads();

    const int nt = ((i0 + 1343) >> 6) + 1;
    for (int t = 0; t < nt; ++t) {
        const int j0 = t * 64;
        const int jb = jb0 + j0;
        const bool more = (t + 1 < nt);

        // ---- QK & QP MFMA (read kbuf, pering) ----
        f32x4 qk[4], qp[5];
        #pragma unroll
        for (int nb = 0; nb < 4; ++nb) qk[nb] = z;
        #pragma unroll
        for (int f = 0; f < 5; ++f) qp[f] = z;
        __builtin_amdgcn_s_setprio(1);
        #pragma unroll
        for (int ks = 0; ks < 2; ++ks) {
            #pragma unroll
            for (int nb = 0; nb < 4; ++nb) {
                int row = nb * 16 + lr;
                bf16x8 kb = *(const bf16x8*)&kbuf[row * 64 + (((4 * ks + lg) ^ (row & 7)) * 8)];
                qk[nb] = __builtin_amdgcn_mfma_f32_16x16x32_bf16(qf[ks], kb, qk[nb], 0, 0, 0);
            }
            #pragma unroll
            for (int f = 0; f < 5; ++f) {
                int rel = 48 - 16 * w + f * 16 + lr;
                int slotp = (jb + rel) & 127;
                bf16x8 pb = *(const bf16x8*)&pering[slotp * 64 + (((4 * ks + lg) ^ (slotp & 7)) * 8)];
                qp[f] = __builtin_amdgcn_mfma_f32_16x16x32_bf16(qf[ks], pb, qp[f], 0, 0, 0);
            }
        }
        __builtin_amdgcn_s_setprio(0);

        VDRAIN();   // retire own V(t) loads (issued after barrier C of t-1)
        SBAR();     // B: publishes V(t); certifies kbuf/pering reads of tile t

        if (more) { // stage K(t+1) and PE(t+1)
            const int j0n = j0 + 64;
            #pragma unroll
            for (int q = 0; q < 2; ++q) {
                int row = 16 * w + 8 * q + rl;
                gload_lds16(kvb + ((size_t)(b * 2304 + j0n + row)) * 2048 + h * 64 + ((cch ^ rl) * 8),
                            &kbuf[(16 * w + 8 * q) * 64]);
            }
            const int A0 = jb + 128;
            #pragma unroll
            for (int q = 0; q < 2; ++q) {
                int rr = A0 + 16 * w + 8 * q;
                int a = rr + rl;
                int srow = a > 2303 ? 2303 : a;
                gload_lds16(peb + ((size_t)(h * 2304 + srow)) * 64 + ((cch ^ rl) * 8),
                            &pering[(rr & 127) * 64]);
            }
        }

        // ---- main: mask + softmax (m == 0), shuffle qp gather ----
        const bool nomask = (j0 + 63 <= iw + 1280);
        #pragma unroll
        for (int jr = 0; jr < 4; ++jr) {
            const int r = lg * 4 + jr;
            const int ia = iw + r;
            const int src = (lane & 48) | ((lr + 15 - r) & 15);
            float rot0 = __shfl(qp[0][jr], src);
            float rot1 = __shfl(qp[1][jr], src);
            float rot2 = __shfl(qp[2][jr], src);
            float rot3 = __shfl(qp[3][jr], src);
            float rot4 = __shfl(qp[4][jr], src);
            const bool hi = (lr > r);
            float s0 = qk[0][jr] + (hi ? rot1 : rot0);
            float s1 = qk[1][jr] + (hi ? rot2 : rot1);
            float s2 = qk[2][jr] + (hi ? rot3 : rot2);
            float s3 = qk[3][jr] + (hi ? rot4 : rot3);
            if (!nomask) {
                s0 = (j0 + lr      <= ia + 1280) ? s0 : -1e30f;
                s1 = (j0 + lr + 16 <= ia + 1280) ? s1 : -1e30f;
                s2 = (j0 + lr + 32 <= ia + 1280) ? s2 : -1e30f;
                s3 = (j0 + lr + 48 <= ia + 1280) ? s3 : -1e30f;
            }
            float p0 = exp2a(s0), p1 = exp2a(s1);
            float p2 = exp2a(s2), p3 = exp2a(s3);
            unsigned pkA = cvtpk(p0, p1), pkB = cvtpk(p2, p3);
            u16* pw = &pls[w][r * 64];
            pw[pwidx[0]] = (u16)pkA; pw[pwidx[1]] = (u16)(pkA >> 16);
            pw[pwidx[2]] = (u16)pkB; pw[pwidx[3]] = (u16)(pkB >> 16);
            lloc[jr] += (p0 + p1) + (p2 + p3);
        }

        // ---- main PV MFMA ----
        __builtin_amdgcn_s_setprio(1);
        #pragma unroll
        for (int ks = 0; ks < 2; ++ks) {
            bf16x8 pa = *(const bf16x8*)&pls[w][pridx[ks]];
            #pragma unroll
            for (int nb = 0; nb < 4; ++nb) {
                int d = nb * 16 + lr;
                bf16x8 vb = *(const bf16x8*)&vbuf[d * 64 + (((4 * ks + lg) ^ (d & 7)) * 8)];
                od[nb] = __builtin_amdgcn_mfma_f32_16x16x32_bf16(pa, vb, od[nb], 0, 0, 0);
            }
        }
        __builtin_amdgcn_s_setprio(0);

        // ---- aux phase-0: kv rows 256..1279 == tiles 4..19 ----
        if (t >= 4 && t <= 19) {
            #pragma unroll
            for (int jr = 0; jr < 4; ++jr) {
                const int r = lg * 4 + jr;
                float p0 = exp2a(qk[0][jr]), p1 = exp2a(qk[1][jr]);
                float p2 = exp2a(qk[2][jr]), p3 = exp2a(qk[3][jr]);
                unsigned pkA = cvtpk(p0, p1), pkB = cvtpk(p2, p3);
                u16* pw = &pls[w][r * 64];
                pw[pwidx[0]] = (u16)pkA; pw[pwidx[1]] = (u16)(pkA >> 16);
                pw[pwidx[2]] = (u16)pkB; pw[pwidx[3]] = (u16)(pkB >> 16);
                ll2[jr] += (p0 + p1) + (p2 + p3);
            }
            __builtin_amdgcn_s_setprio(1);
            #pragma unroll
            for (int ks = 0; ks < 2; ++ks) {
                bf16x8 pa = *(const bf16x8*)&pls[w][pridx[ks]];
                #pragma unroll
                for (int nb = 0; nb < 4; ++nb) {
                    int d = nb * 16 + lr;
                    bf16x8 vb = *(const bf16x8*)&vbuf[d * 64 + (((4 * ks + lg) ^ (d & 7)) * 8)];
                    od2[nb] = __builtin_amdgcn_mfma_f32_16x16x32_bf16(pa, vb, od2[nb], 0, 0, 0);
                }
            }
            __builtin_amdgcn_s_setprio(0);
        }

        VDRAIN();   // retire own K(t+1)/PE(t+1) loads
        SBAR();     // C: publishes kbuf=K(t+1), pering; certifies vbuf/pls reads

        if (more) { // stage V(t+1)
            const int j0n = j0 + 64;
            #pragma unroll
            for (int q = 0; q < 2; ++q) {
                int row = 16 * w + 8 * q + rl;
                gload_lds16(vt + ((size_t)(bh * 64 + row)) * 2304 + j0n + ((cch ^ rl) * 8),
                            &vbuf[(16 * w + 8 * q) * 64]);
            }
        }
    }

    // ---- main epilogue ----
    #pragma unroll
    for (int jr = 0; jr < 4; ++jr) {
        float l = lloc[jr];
        #pragma unroll
        for (int mk = 1; mk < 16; mk <<= 1) l += __shfl_xor(l, mk);
        float inv = 1.f / l;
        int ia = iw + lg * 4 + jr;
        #pragma unroll
        for (int nb = 0; nb < 4; ++nb)
            outb[((size_t)(b * 1024 + ia)) * 1024 + h * 64 + nb * 16 + lr] =
                f2b(od[nb][jr] * inv);
    }
    // ---- aux phase-0 epilogue ----
    #pragma unroll
    for (int jr = 0; jr < 4; ++jr) {
        float l = ll2[jr];
        #pragma unroll
        for (int mk = 1; mk < 16; mk <<= 1) l += __shfl_xor(l, mk);
        float inv = 1.f / l;
        int ig = i0 + 16 * w + lg * 4 + jr;
        #pragma unroll
        for (int nb = 0; nb < 4; ++nb)
            auxo[((size_t)(bh * 1024 + ig)) * 64 + nb * 16 + lr] = od2[nb][jr] * inv;
    }
}

// ---------------- aux phase-1 (compressed KV) + squared diff ----------------
__global__ __launch_bounds__(256) void attn_aux_diff(
    const u16* __restrict__ qb, const u16* __restrict__ ckcv,
    const u16* __restrict__ cvt, const float* __restrict__ auxo,
    float* __restrict__ acc)
{
    __shared__ u16 kbuf[64 * 64];
    __shared__ u16 vbuf[64 * 64];
    __shared__ u16 pls[4][1024];
    __shared__ float red[4];

    const int tid = threadIdx.x;
    const int w = tid >> 6, lane = tid & 63;
    const int lr = lane & 15, lg = lane >> 4;
    const int rl = lane >> 3, cch = lane & 7;
    const int id = blockIdx.x;
    const int slot = id >> 3;
    const int bh = (id & 7) + ((slot >> 4) << 3);
    const int b = bh >> 4, h = bh & 15;
    const int i0 = (slot & 15) * 64;
    const int iw = i0 + 16 * w;

    const int lrh = lr >> 3, lrm = lr & 7;
    int pwidx[4], pridx[2];
    #pragma unroll
    for (int nb = 0; nb < 4; ++nb)
        pwidx[nb] = (((nb * 2 + lrh) ^ (lg * 2)) * 8) + lrm;
    #pragma unroll
    for (int ks = 0; ks < 2; ++ks)
        pridx[ks] = lr * 64 + (((ks * 4 + lg) ^ ((lr >> 2) * 2)) * 8);

    const u16* kbase = ckcv + ((size_t)(b * 256)) * 2048 + h * 64;
    const u16* vbase = cvt + ((size_t)(bh * 64)) * 256;

    bf16x8 qf[2];
    #pragma unroll
    for (int ks = 0; ks < 2; ++ks)
        qf[ks] = *(const bf16x8*)(qb + ((size_t)(b * 1024 + iw + lr)) * 1024
                                  + h * 64 + ks * 32 + lg * 8);

    const f32x4 z = {0.f, 0.f, 0.f, 0.f};
    f32x4 od[4];
    float lloc[4];
    #pragma unroll
    for (int nb = 0; nb < 4; ++nb) od[nb] = z;
    #pragma unroll
    for (int jr = 0; jr < 4; ++jr) lloc[jr] = 0.f;

    for (int t = 0; t < 4; ++t) {
        const int j0 = t * 64;
        __syncthreads();
        #pragma unroll
        for (int q = 0; q < 2; ++q) {
            int row = 16 * w + 8 * q + rl;
            gload_lds16(kbase + (size_t)(j0 + row) * 2048 + ((cch ^ rl) * 8),
                        &kbuf[(16 * w + 8 * q) * 64]);
            gload_lds16(vbase + (size_t)row * 256 + j0 + ((cch ^ rl) * 8),
                        &vbuf[(16 * w + 8 * q) * 64]);
        }
        __syncthreads();

        f32x4 qk[4];
        #pragma unroll
        for (int nb = 0; nb < 4; ++nb) qk[nb] = z;
        #pragma unroll
        for (int ks = 0; ks < 2; ++ks)
            #pragma unroll
            for (int nb = 0; nb < 4; ++nb) {
                int row = nb * 16 + lr;
                bf16x8 kb = *(const bf16x8*)&kbuf[row * 64 + (((4 * ks + lg) ^ (row & 7)) * 8)];
                qk[nb] = __builtin_amdgcn_mfma_f32_16x16x32_bf16(qf[ks], kb, qk[nb], 0, 0, 0);
            }

        #pragma unroll
        for (int jr = 0; jr < 4; ++jr) {
            const int r = lg * 4 + jr;
            float p0 = exp2a(qk[0][jr]), p1 = exp2a(qk[1][jr]);
            float p2 = exp2a(qk[2][jr]), p3 = exp2a(qk[3][jr]);
            unsigned pkA = cvtpk(p0, p1), pkB = cvtpk(p2, p3);
            u16* pw = &pls[w][r * 64];
            pw[pwidx[0]] = (u16)pkA; pw[pwidx[1]] = (u16)(pkA >> 16);
            pw[pwidx[2]] = (u16)pkB; pw[pwidx[3]] = (u16)(pkB >> 16);
            lloc[jr] += (p0 + p1) + (p2 + p3);
        }

        #pragma unroll
        for (int ks = 0; ks < 2; ++ks) {
            bf16x8 pa = *(const bf16x8*)&pls[w][pridx[ks]];
            #pragma unroll
            for (int nb = 0; nb < 4; ++nb) {
                int d = nb * 16 + lr;
                bf16x8 vb = *(const bf16x8*)&vbuf[d * 64 + (((4 * ks + lg) ^ (d & 7)) * 8)];
                od[nb] = __builtin_amdgcn_mfma_f32_16x16x32_bf16(pa, vb, od[nb], 0, 0, 0);
            }
        }
    }

    float local = 0.f;
    #pragma unroll
    for (int jr = 0; jr < 4; ++jr) {
        float l = lloc[jr];
        #pragma unroll
        for (int mk = 1; mk < 16; mk <<= 1) l += __shfl_xor(l, mk);
        float inv = 1.f / l;
        int ig = i0 + 16 * w + lg * 4 + jr;
        #pragma unroll
        for (int nb = 0; nb < 4; ++nb) {
            float o2 = od[nb][jr] * inv;
            float o1 = auxo[((size_t)(bh * 1024 + ig)) * 64 + nb * 16 + lr];
            float d = o1 - o2;
            local += d * d;
        }
    }
    #pragma unroll
    for (int mk = 1; mk < 64; mk <<= 1) local += __shfl_xor(local, mk);
    if (lane == 0) red[w] = local;
    __syncthreads();
    if (tid == 0) atomicAdd(acc, red[0] + red[1] + red[2] + red[3]);
}

__global__ void finish_aux(const float* __restrict__ acc, float* __restrict__ out)
{
    out[0] = acc[0] * (1.0f / 4194304.0f);
}

// ---------------- launch ----------------
extern "C" void kernel_launch(void* const* d_in, const int* in_sizes, int n_in,
                              void* d_out, int out_size, void* d_ws, size_t ws_size,
                              hipStream_t stream)
{
    const float* x     = (const float*)d_in[0];
    const float* mem   = (const float*)d_in[1];
    const float* cmem  = (const float*)d_in[2];
    const float* pos   = (const float*)d_in[3];
    const float* Wq    = (const float*)d_in[5];
    const float* Wkv   = (const float*)d_in[6];
    const float* Wout  = (const float*)d_in[7];
    const float* bout  = (const float*)d_in[8];
    const float* convw = (const float*)d_in[9];
    const float* convb = (const float*)d_in[10];

    float* out      = (float*)d_out;
    float* logits   = out;
    float* new_mem  = out + 4194304;
    float* new_cmem = out + 8388608;
    float* aux_out  = out + 9437184;

    char* p = (char*)d_ws;
    u16* kvb   = (u16*)p; p += (size_t)9216 * 2048 * 2;
    u16* qb    = (u16*)p; p += (size_t)4096 * 1024 * 2;
    u16* kvin  = (u16*)p; p += (size_t)9216 * 1024 * 2;   // becomes vt AFTER all kvin readers done
    u16* wkvt  = (u16*)p; p += (size_t)2048 * 1024 * 2;
    u16* wqt   = (u16*)p; p += (size_t)1024 * 1024 * 2;
    u16* woutt = (u16*)p; p += (size_t)1024 * 1024 * 2;
    u16* w2t   = (u16*)p; p += (size_t)1024 * 4096 * 2;   // becomes cvt AFTER compress GEMM
    u16* peb   = (u16*)p; p += (size_t)16 * 2304 * 64 * 2;
    u16* xb    = (u16*)p; p += (size_t)4096 * 1024 * 2;   // auxo overlay region
    u16* memb  = (u16*)p; p += (size_t)4096 * 1024 * 2;
    u16* cmpb  = (u16*)p; p += (size_t)1024 * 1024 * 2;
    u16* ckcvb = (u16*)p; p += (size_t)1024 * 2048 * 2;
    u16* aob   = (u16*)p; p += (size_t)4096 * 1024 * 2;
    float* acc = (float*)p;
    u16* vt   = kvin;          // 4096 x 2304 u16, exact fit
    u16* cvt  = w2t;           // 4096 x 256 u16, fits
    float* auxo = (float*)xb;  // 4,194,304 f32 == xb+memb region exactly
    (void)memb;

    hipMemcpyAsync(new_mem, x, (size_t)4194304 * sizeof(float),
                   hipMemcpyDeviceToDevice, stream);

    cvt_bf16<<<2304, 256, 0, stream>>>(pos, peb, 589824);
    concat_bf16<<<9216, 256, 0, stream>>>(x, mem, cmem, kvin);
    transpose_bf16<<<dim3(64, 32), 256, 0, stream>>>(Wkv, wkvt, 1024, 2048);
    transpose_bf16<<<dim3(32, 32), 256, 0, stream>>>(Wq, wqt, 1024, 1024);
    transpose_bf16<<<dim3(32, 32), 256, 0, stream>>>(Wout, woutt, 1024, 1024);
    w2t_bf16<<<16384, 256, 0, stream>>>(convw, w2t);

    // ---- all kvin readers FIRST (kvin is clobbered by transpose_v below) ----
    gemm_bf16<<<dim3(16, 72), 256, 0, stream>>>(kvin, wkvt, nullptr, nullptr, kvb, 9216, 2048, 1024, 1.f, 0, 10);
    // Q = x @ Wq; A = kvin rows 1280.. per 2304-row batch (1024-row batches, K=1024)
    gemm_bf16<<<dim3(8, 32), 256, 0, stream>>>(kvin + (size_t)1280 * 1024, wqt, nullptr, nullptr, qb,
                                               4096, 1024, 1024, C2, 1280, 10);
    // compressed = mem @ W2 + convb; A = kvin rows 256.. (256-row batches, K=4096;
    // batch stride 2304*1024 elems = (256+320)*4096 -> apad=320, ashift=8). Reads w2t.
    gemm_bf16<<<dim3(8, 8), 256, 0, stream>>>(kvin + (size_t)256 * 1024, w2t, convb, new_cmem, cmpb,
                                              1024, 1024, 4096, 1.f, 320, 8);
    gemm_bf16<<<dim3(16, 8), 256, 0, stream>>>(cmpb, wkvt, nullptr, nullptr, ckcvb, 1024, 2048, 1024, 1.f, 0, 10);

    // ---- now kvin and w2t are dead: overlay with vt / cvt ----
    transpose_v<<<dim3(36, 64), 256, 0, stream>>>(kvb, 2304, vt);
    transpose_v<<<dim3(4, 64), 256, 0, stream>>>(ckcvb, 256, cvt);

    attn_main_fused<<<1024, 256, 0, stream>>>(qb, kvb, vt, peb, aob, auxo);
    gemm_bf16<<<dim3(8, 32), 256, 0, stream>>>(aob, woutt, bout, logits, nullptr, 4096, 1024, 1024, 1.f, 0, 10);

    hipMemsetAsync(acc, 0, sizeof(float), stream);
    attn_aux_diff<<<1024, 256, 0, stream>>>(qb, ckcvb, cvt, auxo, acc);
    finish_aux<<<1, 1, 0, stream>>>(acc, aux_out);
}